// Round 6
// baseline (1777.281 us; speedup 1.0000x reference)
//
#include <hip/hip_runtime.h>
#include <hip/hip_bf16.h>
#include <math.h>

#define Bn 64
#define Lq 512
#define Dm 128
#define NHh 8
#define ELn 2
#define PLn 96
#define CINn 8
#define DFFn 2048
#define NTFn 4
#define EPSf 1e-5f

typedef __attribute__((ext_vector_type(8))) short short8v;
typedef __attribute__((ext_vector_type(4))) float f32x4;

__device__ __forceinline__ short f2b(float f) {
    union { float f; unsigned u; } v; v.f = f;
    unsigned r = v.u + 0x7fff + ((v.u >> 16) & 1);
    return (short)(r >> 16);
}
__device__ __forceinline__ float fast_tanh(float x) {
    float ax = fabsf(x);
    float e = __expf(2.f * ax);
    float t = 1.f - 2.f / (e + 1.f);
    return copysignf(t, x);
}

// ------------------------------------------------------- fp32 -> bf16
__global__ void cvt_kernel(const float* __restrict__ in, short* __restrict__ out, int n) {
    int i = blockIdx.x * 256 + threadIdx.x;
    if (i < n) out[i] = f2b(in[i]);
}

// ---------------------------------------------------------------- GARCH
__global__ void garch_kernel(const float* __restrict__ x_enc,
                             const float* __restrict__ g_omega,
                             const float* __restrict__ g_alpha,
                             const float* __restrict__ g_beta,
                             const float* __restrict__ g_h0,
                             float* __restrict__ garch) {
    int b = threadIdx.x;
    if (b >= Bn) return;
    float omega = log1pf(__expf(g_omega[0]));
    float alpha = 0.2f / (1.f + __expf(-g_alpha[0]));
    float beta  = 0.8f / (1.f + __expf(-g_beta[0]));
    float h = log1pf(__expf(g_h0[0]));
    const float* xe = x_enc + (size_t)b * Lq * CINn + (CINn - 2);
    for (int t = 0; t < Lq; ++t) {
        float r = xe[(size_t)t * CINn];
        h = omega + alpha * r * r + beta * h;
    }
    float ab = alpha + beta;
    for (int p = 0; p < PLn; ++p) {
        garch[b * PLn + p] = sqrtf(h);
        h = omega + ab * h;
    }
}

// ------------------------------------------------- conv + temporal + pos
__global__ void enc_kernel(const float* __restrict__ x_enc,
                           const float* __restrict__ x_mark,
                           const float* __restrict__ conv_w,
                           const float* __restrict__ temp_w,
                           float* __restrict__ enc) {
    int idx = blockIdx.x * blockDim.x + threadIdx.x;   // over B*L*D
    int d = idx & (Dm - 1);
    int l = (idx >> 7) & (Lq - 1);
    int b = idx >> 16;
    int lm = (l + Lq - 1) & (Lq - 1);
    int lp = (l + 1) & (Lq - 1);
    const float* xb = x_enc + (size_t)b * Lq * CINn;
    const float* w  = conv_w + (size_t)d * CINn * 3;
    float acc = 0.f;
#pragma unroll
    for (int ci = 0; ci < CINn; ++ci) {
        acc += xb[(size_t)lm * CINn + ci] * w[ci * 3 + 0];
        acc += xb[(size_t)l  * CINn + ci] * w[ci * 3 + 1];
        acc += xb[(size_t)lp * CINn + ci] * w[ci * 3 + 2];
    }
    const float* mk = x_mark + ((size_t)b * Lq + l) * NTFn;
    const float* tw = temp_w + (size_t)d * NTFn;
#pragma unroll
    for (int f = 0; f < NTFn; ++f) acc += mk[f] * tw[f];
    float dv = __expf(-(float)(d & ~1) * (9.210340371976184f / 128.f));
    float ang = (float)l * dv;
    acc += (d & 1) ? cosf(ang) : sinf(ang);
    enc[idx] = acc;
}

// ------------------------------------------ fp32 GEMM (kept for xW only)
#define BKt 64
#define LPAD 68
__global__ __launch_bounds__(256) void gemm_kernel(
    const float* __restrict__ A, const float* __restrict__ W,
    const float* __restrict__ b1, const float* __restrict__ b2,
    float* __restrict__ C, int M, int N, int K, int relu)
{
    __shared__ float As[BKt][LPAD];
    __shared__ float Ws[BKt][LPAD];
    int t  = threadIdx.x;
    int tr = t >> 4, tc = t & 15;
    int m0 = blockIdx.x * 64, n0 = blockIdx.y * 64;
    int lr  = t >> 4;
    int lc4 = (t & 15) * 4;
    float acc[4][4] = {};
    for (int k0 = 0; k0 < K; k0 += BKt) {
#pragma unroll
        for (int q = 0; q < 4; ++q) {
            int r = lr + q * 16;
            float4 av = *reinterpret_cast<const float4*>(&A[(size_t)(m0 + r) * K + k0 + lc4]);
            As[lc4 + 0][r] = av.x; As[lc4 + 1][r] = av.y;
            As[lc4 + 2][r] = av.z; As[lc4 + 3][r] = av.w;
            float4 wv = *reinterpret_cast<const float4*>(&W[(size_t)(n0 + r) * K + k0 + lc4]);
            Ws[lc4 + 0][r] = wv.x; Ws[lc4 + 1][r] = wv.y;
            Ws[lc4 + 2][r] = wv.z; Ws[lc4 + 3][r] = wv.w;
        }
        __syncthreads();
#pragma unroll 8
        for (int kk = 0; kk < BKt; ++kk) {
            float4 a  = *reinterpret_cast<const float4*>(&As[kk][tr * 4]);
            float4 bb = *reinterpret_cast<const float4*>(&Ws[kk][tc * 4]);
            float av[4] = {a.x, a.y, a.z, a.w};
            float bv[4] = {bb.x, bb.y, bb.z, bb.w};
#pragma unroll
            for (int i = 0; i < 4; ++i)
#pragma unroll
                for (int j = 0; j < 4; ++j)
                    acc[i][j] += av[i] * bv[j];
        }
        __syncthreads();
    }
#pragma unroll
    for (int i = 0; i < 4; ++i) {
        int m = m0 + tr * 4 + i;
#pragma unroll
        for (int j = 0; j < 4; ++j) {
            int n = n0 + tc * 4 + j;
            float v = acc[i][j] + b1[n] + (b2 ? b2[n] : 0.f);
            if (relu) v = fmaxf(v, 0.f);
            C[(size_t)m * N + n] = v;
        }
    }
}

// ------------------------ bf16 MFMA GEMM, tile 128x128 (4 waves of 64x64)
// C = act(A @ W^T + b1); A: MxK bf16 row-major, W: NxK bf16 row-major.
__global__ __launch_bounds__(256) void gemm_bf16_128(
    const short* __restrict__ A, const short* __restrict__ W,
    const float* __restrict__ b1,
    float* __restrict__ Cf, short* __restrict__ Cb,
    int M, int N, int K, int relu)
{
    int t = threadIdx.x;
    int wid = t >> 6, lane = t & 63;
    int wr = wid >> 1, wc = wid & 1;
    int m0 = blockIdx.x * 128 + wr * 64;
    int n0 = blockIdx.y * 128 + wc * 64;
    int lr = lane & 15;
    int lk = (lane >> 4) * 8;
    f32x4 acc[4][4] = {};
    for (int k0 = 0; k0 < K; k0 += 32) {
        short8v a[4], b[4];
#pragma unroll
        for (int i = 0; i < 4; ++i)
            a[i] = *reinterpret_cast<const short8v*>(&A[(size_t)(m0 + i * 16 + lr) * K + k0 + lk]);
#pragma unroll
        for (int j = 0; j < 4; ++j)
            b[j] = *reinterpret_cast<const short8v*>(&W[(size_t)(n0 + j * 16 + lr) * K + k0 + lk]);
#pragma unroll
        for (int i = 0; i < 4; ++i)
#pragma unroll
            for (int j = 0; j < 4; ++j)
                acc[i][j] = __builtin_amdgcn_mfma_f32_16x16x32_bf16(a[i], b[j], acc[i][j], 0, 0, 0);
    }
    int cr0 = (lane >> 4) * 4;
    int cc = lane & 15;
#pragma unroll
    for (int i = 0; i < 4; ++i)
#pragma unroll
        for (int j = 0; j < 4; ++j) {
            int col = n0 + j * 16 + cc;
            float bias = b1[col];
#pragma unroll
            for (int r = 0; r < 4; ++r) {
                int row = m0 + i * 16 + cr0 + r;
                float v = acc[i][j][r] + bias;
                if (relu) v = fmaxf(v, 0.f);
                if (Cf) Cf[(size_t)row * N + col] = v;
                else    Cb[(size_t)row * N + col] = f2b(v);
            }
        }
}

// ------------------------ bf16 MFMA GEMM, tile 64x64 (4 waves of 32x32)
// for small-N GEMMs (N=128): more blocks -> all CUs busy
__global__ __launch_bounds__(256) void gemm_bf16_64(
    const short* __restrict__ A, const short* __restrict__ W,
    const float* __restrict__ b1,
    float* __restrict__ Cf,
    int M, int N, int K)
{
    int t = threadIdx.x;
    int wid = t >> 6, lane = t & 63;
    int wr = wid >> 1, wc = wid & 1;
    int m0 = blockIdx.x * 64 + wr * 32;
    int n0 = blockIdx.y * 64 + wc * 32;
    int lr = lane & 15;
    int lk = (lane >> 4) * 8;
    f32x4 acc[2][2] = {};
    for (int k0 = 0; k0 < K; k0 += 32) {
        short8v a[2], b[2];
#pragma unroll
        for (int i = 0; i < 2; ++i)
            a[i] = *reinterpret_cast<const short8v*>(&A[(size_t)(m0 + i * 16 + lr) * K + k0 + lk]);
#pragma unroll
        for (int j = 0; j < 2; ++j)
            b[j] = *reinterpret_cast<const short8v*>(&W[(size_t)(n0 + j * 16 + lr) * K + k0 + lk]);
#pragma unroll
        for (int i = 0; i < 2; ++i)
#pragma unroll
            for (int j = 0; j < 2; ++j)
                acc[i][j] = __builtin_amdgcn_mfma_f32_16x16x32_bf16(a[i], b[j], acc[i][j], 0, 0, 0);
    }
    int cr0 = (lane >> 4) * 4;
    int cc = lane & 15;
#pragma unroll
    for (int i = 0; i < 2; ++i)
#pragma unroll
        for (int j = 0; j < 2; ++j) {
            int col = n0 + j * 16 + cc;
            float bias = b1[col];
#pragma unroll
            for (int r = 0; r < 4; ++r) {
                int row = m0 + i * 16 + cr0 + r;
                Cf[(size_t)row * N + col] = acc[i][j][r] + bias;
            }
        }
}

// ---------------------------------------------------------------- LSTM
// 1024 threads: pair (2j, 2j+1) splits gate-row j's 128-dot into two 64-dots
__global__ __launch_bounds__(1024, 4) void lstm_kernel(
    const float* __restrict__ xW, const float* __restrict__ Whh,
    float* __restrict__ xout, short* __restrict__ xb_out)
{
    __shared__ __align__(16) float hbuf[Dm];
    __shared__ float gact[4 * Dm];
    int b = blockIdx.x;
    int tid = threadIdx.x;
    int j = tid >> 1;       // gate row 0..511
    int p = tid & 1;        // k-half
    float w[64];
#pragma unroll
    for (int k = 0; k < 64; k += 4) {
        float4 wv = *reinterpret_cast<const float4*>(&Whh[(size_t)j * Dm + p * 64 + k]);
        w[k] = wv.x; w[k + 1] = wv.y; w[k + 2] = wv.z; w[k + 3] = wv.w;
    }
    float c = 0.f;
    if (tid < Dm) hbuf[tid] = 0.f;
    __syncthreads();
    const float* xwb = xW + (size_t)b * Lq * 512;
    const float* hb = &hbuf[p * 64];
    float xw_next = xwb[j];
    for (int t = 0; t < Lq; ++t) {
        float xw = xw_next;
        int tn = (t + 1 < Lq) ? t + 1 : t;
        xw_next = xwb[(size_t)tn * 512 + j];
        float s0 = 0.f, s1 = 0.f, s2 = 0.f, s3 = 0.f;
#pragma unroll
        for (int k = 0; k < 64; k += 16) {
            float4 h0 = *reinterpret_cast<const float4*>(&hb[k]);
            float4 h1 = *reinterpret_cast<const float4*>(&hb[k + 4]);
            float4 h2 = *reinterpret_cast<const float4*>(&hb[k + 8]);
            float4 h3 = *reinterpret_cast<const float4*>(&hb[k + 12]);
            s0 += w[k] * h0.x + w[k + 1] * h0.y + w[k + 2] * h0.z + w[k + 3] * h0.w;
            s1 += w[k + 4] * h1.x + w[k + 5] * h1.y + w[k + 6] * h1.z + w[k + 7] * h1.w;
            s2 += w[k + 8] * h2.x + w[k + 9] * h2.y + w[k + 10] * h2.z + w[k + 11] * h2.w;
            s3 += w[k + 12] * h3.x + w[k + 13] * h3.y + w[k + 14] * h3.z + w[k + 15] * h3.w;
        }
        float sp = (s0 + s1) + (s2 + s3);
        sp += __shfl_xor(sp, 1);
        float g = xw + sp;
        float a = (j < 2 * Dm || j >= 3 * Dm) ? 1.f / (1.f + __expf(-g)) : fast_tanh(g);
        gact[j] = a;
        __syncthreads();
        if (tid < Dm) {
            c = gact[Dm + tid] * c + gact[tid] * gact[2 * Dm + tid];
            float h = gact[3 * Dm + tid] * fast_tanh(c);
            hbuf[tid] = h;
            size_t o = ((size_t)b * Lq + t) * Dm + tid;
            xout[o] = h;
            xb_out[o] = f2b(h);
        }
        __syncthreads();
    }
}

// ------------------------------------------------------------- attention
__global__ __launch_bounds__(256) void attn_kernel(
    const float* __restrict__ qkv, short* __restrict__ ctxb)
{
    __shared__ float Kb[Lq][16];
    __shared__ float Vb[Lq][16];
    int h = blockIdx.x & (NHh - 1);
    int b = blockIdx.x >> 3;
    int t = threadIdx.x;
    const float* base = qkv + (size_t)b * Lq * 384;
    int hoff = h * 16;
    for (int idx = t; idx < Lq * 16; idx += 256) {
        int row = idx >> 4, col = idx & 15;
        Kb[row][col] = base[(size_t)row * 384 + 128 + hoff + col];
        Vb[row][col] = base[(size_t)row * 384 + 256 + hoff + col];
    }
    __syncthreads();
    for (int rr = 0; rr < 2; ++rr) {
        int l = t + rr * 256;
        float q[16];
#pragma unroll
        for (int cc = 0; cc < 16; ++cc) q[cc] = base[(size_t)l * 384 + hoff + cc];
        float m = -1e30f, ssum = 0.f;
        float acc[16] = {};
        for (int jr = 0; jr < Lq; ++jr) {
            float s = 0.f;
#pragma unroll
            for (int cc = 0; cc < 16; ++cc) s += q[cc] * Kb[jr][cc];
            s *= 0.25f;
            if (s > m) {
                float corr = __expf(m - s);
                ssum *= corr;
#pragma unroll
                for (int cc = 0; cc < 16; ++cc) acc[cc] *= corr;
                m = s;
            }
            float p = __expf(s - m);
            ssum += p;
#pragma unroll
            for (int cc = 0; cc < 16; ++cc) acc[cc] += p * Vb[jr][cc];
        }
        float inv = 1.f / ssum;
        short8v v0, v1;
#pragma unroll
        for (int cc = 0; cc < 8; ++cc) { v0[cc] = f2b(acc[cc] * inv); v1[cc] = f2b(acc[cc + 8] * inv); }
        short* o = ctxb + ((size_t)b * Lq + l) * Dm + hoff;
        *reinterpret_cast<short8v*>(o) = v0;
        *reinterpret_cast<short8v*>(o + 8) = v1;
    }
}

// ----------------------------------------------------- residual add + LN (+ bf16 mirror)
__global__ __launch_bounds__(256) void addln_kernel(
    float* __restrict__ x, const float* __restrict__ add,
    const float* __restrict__ g, const float* __restrict__ bta,
    short* __restrict__ xb)
{
    int wave = threadIdx.x >> 6;
    int lane = threadIdx.x & 63;
    int row = blockIdx.x * 4 + wave;
    float* xr = x + (size_t)row * Dm;
    const float* ar = add + (size_t)row * Dm;
    int d0 = lane * 2;
    float2 xv = *reinterpret_cast<const float2*>(&xr[d0]);
    float2 av = *reinterpret_cast<const float2*>(&ar[d0]);
    float v0 = xv.x + av.x, v1 = xv.y + av.y;
    float s = v0 + v1;
#pragma unroll
    for (int off = 32; off > 0; off >>= 1) s += __shfl_xor(s, off);
    float mu = s * (1.f / Dm);
    float e0 = v0 - mu, e1 = v1 - mu;
    float s2 = e0 * e0 + e1 * e1;
#pragma unroll
    for (int off = 32; off > 0; off >>= 1) s2 += __shfl_xor(s2, off);
    float rs = rsqrtf(s2 * (1.f / Dm) + EPSf);
    float o0 = e0 * rs * g[d0] + bta[d0];
    float o1 = e1 * rs * g[d0 + 1] + bta[d0 + 1];
    xr[d0] = o0;
    xr[d0 + 1] = o1;
    unsigned pk = (unsigned)(unsigned short)f2b(o0) | ((unsigned)(unsigned short)f2b(o1) << 16);
    *reinterpret_cast<unsigned*>(&xb[(size_t)row * Dm + d0]) = pk;
}

// --------------------------------------------------------------- head
__global__ void head_kernel(const float* __restrict__ x,
                            const float* __restrict__ head_w, const float* __restrict__ head_b,
                            const float* __restrict__ gw1, const float* __restrict__ gb1,
                            const float* __restrict__ gw2, const float* __restrict__ gb2,
                            const float* __restrict__ garch,
                            float* __restrict__ out)
{
    __shared__ float last[Dm];
    __shared__ float t1[Dm / 2];
    int b = blockIdx.x, t = threadIdx.x;
    if (t < Dm) last[t] = x[((size_t)b * Lq + (Lq - 1)) * Dm + t];
    __syncthreads();
    if (t < Dm / 2) {
        float s = gb1[t];
#pragma unroll 8
        for (int d = 0; d < Dm; ++d) s += last[d] * gw1[(size_t)t * Dm + d];
        t1[t] = fmaxf(s, 0.f);
    }
    __syncthreads();
    if (t < PLn) {
        float ai = head_b[t];
#pragma unroll 8
        for (int d = 0; d < Dm; ++d) ai += last[d] * head_w[(size_t)t * Dm + d];
        float gg = gb2[t];
#pragma unroll 8
        for (int j = 0; j < Dm / 2; ++j) gg += t1[j] * gw2[(size_t)t * (Dm / 2) + j];
        float gate = 1.f / (1.f + __expf(-gg));
        out[b * PLn + t] = garch[b * PLn + t] + gate * ai;
    }
}

extern "C" void kernel_launch(void* const* d_in, const int* in_sizes, int n_in,
                              void* d_out, int out_size, void* d_ws, size_t ws_size,
                              hipStream_t stream)
{
    const float* x_enc  = (const float*)d_in[0];
    const float* x_mark = (const float*)d_in[1];
    const float* conv_w = (const float*)d_in[4];
    const float* temp_w = (const float*)d_in[5];
    const float* Wih    = (const float*)d_in[6];
    const float* Whh    = (const float*)d_in[7];
    const float* bih    = (const float*)d_in[8];
    const float* bhh    = (const float*)d_in[9];
    const float* Wqkv   = (const float*)d_in[10];
    const float* bqkv   = (const float*)d_in[11];
    const float* Wo     = (const float*)d_in[12];
    const float* bo     = (const float*)d_in[13];
    const float* ln1g   = (const float*)d_in[14];
    const float* ln1b   = (const float*)d_in[15];
    const float* W1     = (const float*)d_in[16];
    const float* b1     = (const float*)d_in[17];
    const float* W2     = (const float*)d_in[18];
    const float* b2     = (const float*)d_in[19];
    const float* ln2g   = (const float*)d_in[20];
    const float* ln2b   = (const float*)d_in[21];
    const float* head_w = (const float*)d_in[22];
    const float* head_b = (const float*)d_in[23];
    const float* gw1    = (const float*)d_in[24];
    const float* gb1    = (const float*)d_in[25];
    const float* gw2    = (const float*)d_in[26];
    const float* gb2    = (const float*)d_in[27];
    const float* g_omega= (const float*)d_in[28];
    const float* g_alpha= (const float*)d_in[29];
    const float* g_beta = (const float*)d_in[30];
    const float* g_h0   = (const float*)d_in[31];

    const int M = Bn * Lq;                    // 32768
    float* ws    = (float*)d_ws;
    float* garch = ws;                        // 8192 floats
    float* regionA = ws + 8192;               // 4,194,304 floats
    float* enc  = regionA;                    //   fp32 enc (dead after xW gemm)
    short* xb   = (short*)regionA;            //   bf16 x mirror (after lstm)
    short* ctxb = (short*)(regionA + 2097152);//   bf16 ctx
    float* xWr  = regionA + 4194304;          // 16,777,216 floats
    float* xW   = xWr;                        //   fp32 xW (dead after lstm)
    short* ff1b = (short*)xWr;                //   bf16 ff1 chunk (16384x2048)
    float* x    = xWr + 16777216;             // 4,194,304 floats (live all launch)
    float* qkvr = x + 4194304;                // 12,582,912 floats
    float* qkv  = qkvr;                       //   fp32 qkv
    float* tmp  = qkvr;                       //   fp32 tmp (qkv dead when written)
    float* wbr  = qkvr + 12582912;            // 589,824 floats of bf16 weights
    short* Wqkv_b = (short*)wbr;              // 98,304
    short* Wo_b   = Wqkv_b + 98304;           // 32,768
    short* W1_b   = Wo_b + 32768;             // 524,288
    short* W2_b   = W1_b + 524288;            // 524,288

    // weight conversions (cheap, every launch for determinism)
    cvt_kernel<<<(98304 + 255) / 256, 256, 0, stream>>>(Wqkv, Wqkv_b, 98304);
    cvt_kernel<<<(32768 + 255) / 256, 256, 0, stream>>>(Wo, Wo_b, 32768);
    cvt_kernel<<<(524288 + 255) / 256, 256, 0, stream>>>(W1, W1_b, 524288);
    cvt_kernel<<<(524288 + 255) / 256, 256, 0, stream>>>(W2, W2_b, 524288);

    garch_kernel<<<1, 64, 0, stream>>>(x_enc, g_omega, g_alpha, g_beta, g_h0, garch);
    enc_kernel<<<(Bn * Lq * Dm) / 256, 256, 0, stream>>>(x_enc, x_mark, conv_w, temp_w, enc);
    gemm_kernel<<<dim3(M / 64, 512 / 64), 256, 0, stream>>>(enc, Wih, bih, bhh, xW, M, 512, Dm, 0);
    lstm_kernel<<<Bn, 1024, 0, stream>>>(xW, Whh, x, xb);

    for (int li = 0; li < ELn; ++li) {
        gemm_bf16_128<<<dim3(M / 128, 384 / 128), 256, 0, stream>>>(
            xb, Wqkv_b + (size_t)li * 384 * Dm, bqkv + li * 384, qkv, nullptr, M, 384, Dm, 0);
        attn_kernel<<<Bn * NHh, 256, 0, stream>>>(qkv, ctxb);
        gemm_bf16_64<<<dim3(M / 64, Dm / 64), 256, 0, stream>>>(
            ctxb, Wo_b + (size_t)li * Dm * Dm, bo + li * Dm, tmp, M, Dm, Dm);
        addln_kernel<<<M / 4, 256, 0, stream>>>(x, tmp, ln1g + li * Dm, ln1b + li * Dm, xb);
        for (int mc = 0; mc < 2; ++mc) {
            const int MC = M / 2;             // 16384 rows
            gemm_bf16_128<<<dim3(MC / 128, DFFn / 128), 256, 0, stream>>>(
                xb + (size_t)mc * MC * Dm, W1_b + (size_t)li * DFFn * Dm, b1 + li * DFFn,
                nullptr, ff1b, MC, DFFn, Dm, 1);
            gemm_bf16_64<<<dim3(MC / 64, Dm / 64), 256, 0, stream>>>(
                ff1b, W2_b + (size_t)li * Dm * DFFn, b2 + li * Dm,
                tmp + (size_t)mc * MC * Dm, MC, Dm, DFFn);
        }
        addln_kernel<<<M / 4, 256, 0, stream>>>(x, tmp, ln2g + li * Dm, ln2b + li * Dm, xb);
    }
    head_kernel<<<Bn, 128, 0, stream>>>(x, head_w, head_b, gw1, gb1, gw2, gb2, garch,
                                        (float*)d_out);
}

// Round 7
// 1775.509 us; speedup vs baseline: 1.0010x; 1.0010x over previous
//
#include <hip/hip_runtime.h>
#include <hip/hip_bf16.h>
#include <math.h>

#define Bn 64
#define Lq 512
#define Dm 128
#define NHh 8
#define ELn 2
#define PLn 96
#define CINn 8
#define DFFn 2048
#define NTFn 4
#define EPSf 1e-5f

typedef __attribute__((ext_vector_type(8))) short short8v;
typedef __attribute__((ext_vector_type(4))) float f32x4;

__device__ __forceinline__ short f2b(float f) {
    union { float f; unsigned u; } v; v.f = f;
    unsigned r = v.u + 0x7fff + ((v.u >> 16) & 1);
    return (short)(r >> 16);
}
__device__ __forceinline__ float fast_tanh(float x) {
    float ax = fabsf(x);
    float e = __expf(2.f * ax);
    float t = 1.f - 2.f / (e + 1.f);
    return copysignf(t, x);
}

// ------------------------------------------------------- fp32 -> bf16
__global__ void cvt_kernel(const float* __restrict__ in, short* __restrict__ out, int n) {
    int i = blockIdx.x * 256 + threadIdx.x;
    if (i < n) out[i] = f2b(in[i]);
}

// ---------------------------------------------------------------- GARCH
__global__ void garch_kernel(const float* __restrict__ x_enc,
                             const float* __restrict__ g_omega,
                             const float* __restrict__ g_alpha,
                             const float* __restrict__ g_beta,
                             const float* __restrict__ g_h0,
                             float* __restrict__ garch) {
    int b = threadIdx.x;
    if (b >= Bn) return;
    float omega = log1pf(__expf(g_omega[0]));
    float alpha = 0.2f / (1.f + __expf(-g_alpha[0]));
    float beta  = 0.8f / (1.f + __expf(-g_beta[0]));
    float h = log1pf(__expf(g_h0[0]));
    const float* xe = x_enc + (size_t)b * Lq * CINn + (CINn - 2);
    for (int t = 0; t < Lq; ++t) {
        float r = xe[(size_t)t * CINn];
        h = omega + alpha * r * r + beta * h;
    }
    float ab = alpha + beta;
    for (int p = 0; p < PLn; ++p) {
        garch[b * PLn + p] = sqrtf(h);
        h = omega + ab * h;
    }
}

// ------------------------------------------------- conv + temporal + pos
__global__ void enc_kernel(const float* __restrict__ x_enc,
                           const float* __restrict__ x_mark,
                           const float* __restrict__ conv_w,
                           const float* __restrict__ temp_w,
                           float* __restrict__ enc) {
    int idx = blockIdx.x * blockDim.x + threadIdx.x;   // over B*L*D
    int d = idx & (Dm - 1);
    int l = (idx >> 7) & (Lq - 1);
    int b = idx >> 16;
    int lm = (l + Lq - 1) & (Lq - 1);
    int lp = (l + 1) & (Lq - 1);
    const float* xb = x_enc + (size_t)b * Lq * CINn;
    const float* w  = conv_w + (size_t)d * CINn * 3;
    float acc = 0.f;
#pragma unroll
    for (int ci = 0; ci < CINn; ++ci) {
        acc += xb[(size_t)lm * CINn + ci] * w[ci * 3 + 0];
        acc += xb[(size_t)l  * CINn + ci] * w[ci * 3 + 1];
        acc += xb[(size_t)lp * CINn + ci] * w[ci * 3 + 2];
    }
    const float* mk = x_mark + ((size_t)b * Lq + l) * NTFn;
    const float* tw = temp_w + (size_t)d * NTFn;
#pragma unroll
    for (int f = 0; f < NTFn; ++f) acc += mk[f] * tw[f];
    float dv = __expf(-(float)(d & ~1) * (9.210340371976184f / 128.f));
    float ang = (float)l * dv;
    acc += (d & 1) ? cosf(ang) : sinf(ang);
    enc[idx] = acc;
}

// ------------------------------------------ fp32 GEMM (kept for xW only)
#define BKt 64
#define LPAD 68
__global__ __launch_bounds__(256) void gemm_kernel(
    const float* __restrict__ A, const float* __restrict__ W,
    const float* __restrict__ b1, const float* __restrict__ b2,
    float* __restrict__ C, int M, int N, int K, int relu)
{
    __shared__ float As[BKt][LPAD];
    __shared__ float Ws[BKt][LPAD];
    int t  = threadIdx.x;
    int tr = t >> 4, tc = t & 15;
    int m0 = blockIdx.x * 64, n0 = blockIdx.y * 64;
    int lr  = t >> 4;
    int lc4 = (t & 15) * 4;
    float acc[4][4] = {};
    for (int k0 = 0; k0 < K; k0 += BKt) {
#pragma unroll
        for (int q = 0; q < 4; ++q) {
            int r = lr + q * 16;
            float4 av = *reinterpret_cast<const float4*>(&A[(size_t)(m0 + r) * K + k0 + lc4]);
            As[lc4 + 0][r] = av.x; As[lc4 + 1][r] = av.y;
            As[lc4 + 2][r] = av.z; As[lc4 + 3][r] = av.w;
            float4 wv = *reinterpret_cast<const float4*>(&W[(size_t)(n0 + r) * K + k0 + lc4]);
            Ws[lc4 + 0][r] = wv.x; Ws[lc4 + 1][r] = wv.y;
            Ws[lc4 + 2][r] = wv.z; Ws[lc4 + 3][r] = wv.w;
        }
        __syncthreads();
#pragma unroll 8
        for (int kk = 0; kk < BKt; ++kk) {
            float4 a  = *reinterpret_cast<const float4*>(&As[kk][tr * 4]);
            float4 bb = *reinterpret_cast<const float4*>(&Ws[kk][tc * 4]);
            float av[4] = {a.x, a.y, a.z, a.w};
            float bv[4] = {bb.x, bb.y, bb.z, bb.w};
#pragma unroll
            for (int i = 0; i < 4; ++i)
#pragma unroll
                for (int j = 0; j < 4; ++j)
                    acc[i][j] += av[i] * bv[j];
        }
        __syncthreads();
    }
#pragma unroll
    for (int i = 0; i < 4; ++i) {
        int m = m0 + tr * 4 + i;
#pragma unroll
        for (int j = 0; j < 4; ++j) {
            int n = n0 + tc * 4 + j;
            float v = acc[i][j] + b1[n] + (b2 ? b2[n] : 0.f);
            if (relu) v = fmaxf(v, 0.f);
            C[(size_t)m * N + n] = v;
        }
    }
}

// ------------------------ bf16 MFMA GEMM, tile 128x128 (4 waves of 64x64)
// C = act(A @ W^T + b1); A: MxK bf16 row-major, W: NxK bf16 row-major.
__global__ __launch_bounds__(256) void gemm_bf16_128(
    const short* __restrict__ A, const short* __restrict__ W,
    const float* __restrict__ b1,
    float* __restrict__ Cf, short* __restrict__ Cb,
    int M, int N, int K, int relu)
{
    int t = threadIdx.x;
    int wid = t >> 6, lane = t & 63;
    int wr = wid >> 1, wc = wid & 1;
    int m0 = blockIdx.x * 128 + wr * 64;
    int n0 = blockIdx.y * 128 + wc * 64;
    int lr = lane & 15;
    int lk = (lane >> 4) * 8;
    f32x4 acc[4][4] = {};
    for (int k0 = 0; k0 < K; k0 += 32) {
        short8v a[4], b[4];
#pragma unroll
        for (int i = 0; i < 4; ++i)
            a[i] = *reinterpret_cast<const short8v*>(&A[(size_t)(m0 + i * 16 + lr) * K + k0 + lk]);
#pragma unroll
        for (int j = 0; j < 4; ++j)
            b[j] = *reinterpret_cast<const short8v*>(&W[(size_t)(n0 + j * 16 + lr) * K + k0 + lk]);
#pragma unroll
        for (int i = 0; i < 4; ++i)
#pragma unroll
            for (int j = 0; j < 4; ++j)
                acc[i][j] = __builtin_amdgcn_mfma_f32_16x16x32_bf16(a[i], b[j], acc[i][j], 0, 0, 0);
    }
    int cr0 = (lane >> 4) * 4;
    int cc = lane & 15;
#pragma unroll
    for (int i = 0; i < 4; ++i)
#pragma unroll
        for (int j = 0; j < 4; ++j) {
            int col = n0 + j * 16 + cc;
            float bias = b1[col];
#pragma unroll
            for (int r = 0; r < 4; ++r) {
                int row = m0 + i * 16 + cr0 + r;
                float v = acc[i][j][r] + bias;
                if (relu) v = fmaxf(v, 0.f);
                if (Cf) Cf[(size_t)row * N + col] = v;
                else    Cb[(size_t)row * N + col] = f2b(v);
            }
        }
}

// ------------------------ bf16 MFMA GEMM, tile 64x64 (4 waves of 32x32)
// for small-N GEMMs (N=128): more blocks -> all CUs busy
__global__ __launch_bounds__(256) void gemm_bf16_64(
    const short* __restrict__ A, const short* __restrict__ W,
    const float* __restrict__ b1,
    float* __restrict__ Cf,
    int M, int N, int K)
{
    int t = threadIdx.x;
    int wid = t >> 6, lane = t & 63;
    int wr = wid >> 1, wc = wid & 1;
    int m0 = blockIdx.x * 64 + wr * 32;
    int n0 = blockIdx.y * 64 + wc * 32;
    int lr = lane & 15;
    int lk = (lane >> 4) * 8;
    f32x4 acc[2][2] = {};
    for (int k0 = 0; k0 < K; k0 += 32) {
        short8v a[2], b[2];
#pragma unroll
        for (int i = 0; i < 2; ++i)
            a[i] = *reinterpret_cast<const short8v*>(&A[(size_t)(m0 + i * 16 + lr) * K + k0 + lk]);
#pragma unroll
        for (int j = 0; j < 2; ++j)
            b[j] = *reinterpret_cast<const short8v*>(&W[(size_t)(n0 + j * 16 + lr) * K + k0 + lk]);
#pragma unroll
        for (int i = 0; i < 2; ++i)
#pragma unroll
            for (int j = 0; j < 2; ++j)
                acc[i][j] = __builtin_amdgcn_mfma_f32_16x16x32_bf16(a[i], b[j], acc[i][j], 0, 0, 0);
    }
    int cr0 = (lane >> 4) * 4;
    int cc = lane & 15;
#pragma unroll
    for (int i = 0; i < 2; ++i)
#pragma unroll
        for (int j = 0; j < 2; ++j) {
            int col = n0 + j * 16 + cc;
            float bias = b1[col];
#pragma unroll
            for (int r = 0; r < 4; ++r) {
                int row = m0 + i * 16 + cr0 + r;
                Cf[(size_t)row * N + col] = acc[i][j][r] + bias;
            }
        }
}

// ---------------------------------------------------------------- LSTM
// 1024 threads: pair (2j, 2j+1) splits gate-row j's 128-dot into two 64-dots
__global__ __launch_bounds__(1024, 4) void lstm_kernel(
    const float* __restrict__ xW, const float* __restrict__ Whh,
    float* __restrict__ xout, short* __restrict__ xb_out)
{
    __shared__ __align__(16) float hbuf[Dm];
    __shared__ float gact[4 * Dm];
    int b = blockIdx.x;
    int tid = threadIdx.x;
    int j = tid >> 1;       // gate row 0..511
    int p = tid & 1;        // k-half
    float w[64];
#pragma unroll
    for (int k = 0; k < 64; k += 4) {
        float4 wv = *reinterpret_cast<const float4*>(&Whh[(size_t)j * Dm + p * 64 + k]);
        w[k] = wv.x; w[k + 1] = wv.y; w[k + 2] = wv.z; w[k + 3] = wv.w;
    }
    float c = 0.f;
    if (tid < Dm) hbuf[tid] = 0.f;
    __syncthreads();
    const float* xwb = xW + (size_t)b * Lq * 512;
    const float* hb = &hbuf[p * 64];
    float xw_next = xwb[j];
    for (int t = 0; t < Lq; ++t) {
        float xw = xw_next;
        int tn = (t + 1 < Lq) ? t + 1 : t;
        xw_next = xwb[(size_t)tn * 512 + j];
        float s0 = 0.f, s1 = 0.f, s2 = 0.f, s3 = 0.f;
#pragma unroll
        for (int k = 0; k < 64; k += 16) {
            float4 h0 = *reinterpret_cast<const float4*>(&hb[k]);
            float4 h1 = *reinterpret_cast<const float4*>(&hb[k + 4]);
            float4 h2 = *reinterpret_cast<const float4*>(&hb[k + 8]);
            float4 h3 = *reinterpret_cast<const float4*>(&hb[k + 12]);
            s0 += w[k] * h0.x + w[k + 1] * h0.y + w[k + 2] * h0.z + w[k + 3] * h0.w;
            s1 += w[k + 4] * h1.x + w[k + 5] * h1.y + w[k + 6] * h1.z + w[k + 7] * h1.w;
            s2 += w[k + 8] * h2.x + w[k + 9] * h2.y + w[k + 10] * h2.z + w[k + 11] * h2.w;
            s3 += w[k + 12] * h3.x + w[k + 13] * h3.y + w[k + 14] * h3.z + w[k + 15] * h3.w;
        }
        float sp = (s0 + s1) + (s2 + s3);
        sp += __shfl_xor(sp, 1);
        float g = xw + sp;
        float a = (j < 2 * Dm || j >= 3 * Dm) ? 1.f / (1.f + __expf(-g)) : fast_tanh(g);
        gact[j] = a;
        __syncthreads();
        if (tid < Dm) {
            c = gact[Dm + tid] * c + gact[tid] * gact[2 * Dm + tid];
            float h = gact[3 * Dm + tid] * fast_tanh(c);
            hbuf[tid] = h;
            size_t o = ((size_t)b * Lq + t) * Dm + tid;
            xout[o] = h;
            xb_out[o] = f2b(h);
        }
        __syncthreads();
    }
}

// ------------------------------------------------------------- attention
__global__ __launch_bounds__(256) void attn_kernel(
    const float* __restrict__ qkv, short* __restrict__ ctxb)
{
    __shared__ float Kb[Lq][16];
    __shared__ float Vb[Lq][16];
    int h = blockIdx.x & (NHh - 1);
    int b = blockIdx.x >> 3;
    int t = threadIdx.x;
    const float* base = qkv + (size_t)b * Lq * 384;
    int hoff = h * 16;
    for (int idx = t; idx < Lq * 16; idx += 256) {
        int row = idx >> 4, col = idx & 15;
        Kb[row][col] = base[(size_t)row * 384 + 128 + hoff + col];
        Vb[row][col] = base[(size_t)row * 384 + 256 + hoff + col];
    }
    __syncthreads();
    for (int rr = 0; rr < 2; ++rr) {
        int l = t + rr * 256;
        float q[16];
#pragma unroll
        for (int cc = 0; cc < 16; ++cc) q[cc] = base[(size_t)l * 384 + hoff + cc];
        float m = -1e30f, ssum = 0.f;
        float acc[16] = {};
        for (int jr = 0; jr < Lq; ++jr) {
            float s = 0.f;
#pragma unroll
            for (int cc = 0; cc < 16; ++cc) s += q[cc] * Kb[jr][cc];
            s *= 0.25f;
            if (s > m) {
                float corr = __expf(m - s);
                ssum *= corr;
#pragma unroll
                for (int cc = 0; cc < 16; ++cc) acc[cc] *= corr;
                m = s;
            }
            float p = __expf(s - m);
            ssum += p;
#pragma unroll
            for (int cc = 0; cc < 16; ++cc) acc[cc] += p * Vb[jr][cc];
        }
        float inv = 1.f / ssum;
        short8v v0, v1;
#pragma unroll
        for (int cc = 0; cc < 8; ++cc) { v0[cc] = f2b(acc[cc] * inv); v1[cc] = f2b(acc[cc + 8] * inv); }
        short* o = ctxb + ((size_t)b * Lq + l) * Dm + hoff;
        *reinterpret_cast<short8v*>(o) = v0;
        *reinterpret_cast<short8v*>(o + 8) = v1;
    }
}

// ----------------------------------------------------- residual add + LN (+ bf16 mirror)
__global__ __launch_bounds__(256) void addln_kernel(
    float* __restrict__ x, const float* __restrict__ add,
    const float* __restrict__ g, const float* __restrict__ bta,
    short* __restrict__ xb)
{
    int wave = threadIdx.x >> 6;
    int lane = threadIdx.x & 63;
    int row = blockIdx.x * 4 + wave;
    float* xr = x + (size_t)row * Dm;
    const float* ar = add + (size_t)row * Dm;
    int d0 = lane * 2;
    float2 xv = *reinterpret_cast<const float2*>(&xr[d0]);
    float2 av = *reinterpret_cast<const float2*>(&ar[d0]);
    float v0 = xv.x + av.x, v1 = xv.y + av.y;
    float s = v0 + v1;
#pragma unroll
    for (int off = 32; off > 0; off >>= 1) s += __shfl_xor(s, off);
    float mu = s * (1.f / Dm);
    float e0 = v0 - mu, e1 = v1 - mu;
    float s2 = e0 * e0 + e1 * e1;
#pragma unroll
    for (int off = 32; off > 0; off >>= 1) s2 += __shfl_xor(s2, off);
    float rs = rsqrtf(s2 * (1.f / Dm) + EPSf);
    float o0 = e0 * rs * g[d0] + bta[d0];
    float o1 = e1 * rs * g[d0 + 1] + bta[d0 + 1];
    xr[d0] = o0;
    xr[d0 + 1] = o1;
    unsigned pk = (unsigned)(unsigned short)f2b(o0) | ((unsigned)(unsigned short)f2b(o1) << 16);
    *reinterpret_cast<unsigned*>(&xb[(size_t)row * Dm + d0]) = pk;
}

// --------------------------------------------------------------- head
__global__ void head_kernel(const float* __restrict__ x,
                            const float* __restrict__ head_w, const float* __restrict__ head_b,
                            const float* __restrict__ gw1, const float* __restrict__ gb1,
                            const float* __restrict__ gw2, const float* __restrict__ gb2,
                            const float* __restrict__ garch,
                            float* __restrict__ out)
{
    __shared__ float last[Dm];
    __shared__ float t1[Dm / 2];
    int b = blockIdx.x, t = threadIdx.x;
    if (t < Dm) last[t] = x[((size_t)b * Lq + (Lq - 1)) * Dm + t];
    __syncthreads();
    if (t < Dm / 2) {
        float s = gb1[t];
#pragma unroll 8
        for (int d = 0; d < Dm; ++d) s += last[d] * gw1[(size_t)t * Dm + d];
        t1[t] = fmaxf(s, 0.f);
    }
    __syncthreads();
    if (t < PLn) {
        float ai = head_b[t];
#pragma unroll 8
        for (int d = 0; d < Dm; ++d) ai += last[d] * head_w[(size_t)t * Dm + d];
        float gg = gb2[t];
#pragma unroll 8
        for (int j = 0; j < Dm / 2; ++j) gg += t1[j] * gw2[(size_t)t * (Dm / 2) + j];
        float gate = 1.f / (1.f + __expf(-gg));
        out[b * PLn + t] = garch[b * PLn + t] + gate * ai;
    }
}

extern "C" void kernel_launch(void* const* d_in, const int* in_sizes, int n_in,
                              void* d_out, int out_size, void* d_ws, size_t ws_size,
                              hipStream_t stream)
{
    const float* x_enc  = (const float*)d_in[0];
    const float* x_mark = (const float*)d_in[1];
    const float* conv_w = (const float*)d_in[4];
    const float* temp_w = (const float*)d_in[5];
    const float* Wih    = (const float*)d_in[6];
    const float* Whh    = (const float*)d_in[7];
    const float* bih    = (const float*)d_in[8];
    const float* bhh    = (const float*)d_in[9];
    const float* Wqkv   = (const float*)d_in[10];
    const float* bqkv   = (const float*)d_in[11];
    const float* Wo     = (const float*)d_in[12];
    const float* bo     = (const float*)d_in[13];
    const float* ln1g   = (const float*)d_in[14];
    const float* ln1b   = (const float*)d_in[15];
    const float* W1     = (const float*)d_in[16];
    const float* b1     = (const float*)d_in[17];
    const float* W2     = (const float*)d_in[18];
    const float* b2     = (const float*)d_in[19];
    const float* ln2g   = (const float*)d_in[20];
    const float* ln2b   = (const float*)d_in[21];
    const float* head_w = (const float*)d_in[22];
    const float* head_b = (const float*)d_in[23];
    const float* gw1    = (const float*)d_in[24];
    const float* gb1    = (const float*)d_in[25];
    const float* gw2    = (const float*)d_in[26];
    const float* gb2    = (const float*)d_in[27];
    const float* g_omega= (const float*)d_in[28];
    const float* g_alpha= (const float*)d_in[29];
    const float* g_beta = (const float*)d_in[30];
    const float* g_h0   = (const float*)d_in[31];

    const int M = Bn * Lq;                    // 32768
    float* ws    = (float*)d_ws;
    float* garch = ws;                        // 8192 floats
    float* regionA = ws + 8192;               // 4,194,304 floats
    float* enc  = regionA;                    //   fp32 enc (dead after xW gemm)
    short* xb   = (short*)regionA;            //   bf16 x mirror (after lstm)
    short* ctxb = (short*)(regionA + 2097152);//   bf16 ctx
    float* xWr  = regionA + 4194304;          // 16,777,216 floats
    float* xW   = xWr;                        //   fp32 xW (dead after lstm)
    short* ff1b = (short*)xWr;                //   bf16 ff1 chunk (16384x2048)
    float* x    = xWr + 16777216;             // 4,194,304 floats (live all launch)
    float* qkvr = x + 4194304;                // 12,582,912 floats
    float* qkv  = qkvr;                       //   fp32 qkv
    float* tmp  = qkvr;                       //   fp32 tmp (qkv dead when written)
    float* wbr  = qkvr + 12582912;            // 589,824 floats of bf16 weights
    short* Wqkv_b = (short*)wbr;              // 98,304
    short* Wo_b   = Wqkv_b + 98304;           // 32,768
    short* W1_b   = Wo_b + 32768;             // 524,288
    short* W2_b   = W1_b + 524288;            // 524,288

    // weight conversions (cheap, every launch for determinism)
    cvt_kernel<<<(98304 + 255) / 256, 256, 0, stream>>>(Wqkv, Wqkv_b, 98304);
    cvt_kernel<<<(32768 + 255) / 256, 256, 0, stream>>>(Wo, Wo_b, 32768);
    cvt_kernel<<<(524288 + 255) / 256, 256, 0, stream>>>(W1, W1_b, 524288);
    cvt_kernel<<<(524288 + 255) / 256, 256, 0, stream>>>(W2, W2_b, 524288);

    garch_kernel<<<1, 64, 0, stream>>>(x_enc, g_omega, g_alpha, g_beta, g_h0, garch);
    enc_kernel<<<(Bn * Lq * Dm) / 256, 256, 0, stream>>>(x_enc, x_mark, conv_w, temp_w, enc);
    gemm_kernel<<<dim3(M / 64, 512 / 64), 256, 0, stream>>>(enc, Wih, bih, bhh, xW, M, 512, Dm, 0);
    lstm_kernel<<<Bn, 1024, 0, stream>>>(xW, Whh, x, xb);

    for (int li = 0; li < ELn; ++li) {
        gemm_bf16_128<<<dim3(M / 128, 384 / 128), 256, 0, stream>>>(
            xb, Wqkv_b + (size_t)li * 384 * Dm, bqkv + li * 384, qkv, nullptr, M, 384, Dm, 0);
        attn_kernel<<<Bn * NHh, 256, 0, stream>>>(qkv, ctxb);
        gemm_bf16_64<<<dim3(M / 64, Dm / 64), 256, 0, stream>>>(
            ctxb, Wo_b + (size_t)li * Dm * Dm, bo + li * Dm, tmp, M, Dm, Dm);
        addln_kernel<<<M / 4, 256, 0, stream>>>(x, tmp, ln1g + li * Dm, ln1b + li * Dm, xb);
        for (int mc = 0; mc < 2; ++mc) {
            const int MC = M / 2;             // 16384 rows
            gemm_bf16_128<<<dim3(MC / 128, DFFn / 128), 256, 0, stream>>>(
                xb + (size_t)mc * MC * Dm, W1_b + (size_t)li * DFFn * Dm, b1 + li * DFFn,
                nullptr, ff1b, MC, DFFn, Dm, 1);
            gemm_bf16_64<<<dim3(MC / 64, Dm / 64), 256, 0, stream>>>(
                ff1b, W2_b + (size_t)li * Dm * DFFn, b2 + li * Dm,
                tmp + (size_t)mc * MC * Dm, MC, Dm, DFFn);
        }
        addln_kernel<<<M / 4, 256, 0, stream>>>(x, tmp, ln2g + li * Dm, ln2b + li * Dm, xb);
    }
    head_kernel<<<Bn, 128, 0, stream>>>(x, head_w, head_b, gw1, gb1, gw2, gb2, garch,
                                        (float*)d_out);
}

// Round 8
// 1568.474 us; speedup vs baseline: 1.1331x; 1.1320x over previous
//
#include <hip/hip_runtime.h>
#include <hip/hip_bf16.h>
#include <math.h>

#define Bn 64
#define Lq 512
#define Dm 128
#define NHh 8
#define ELn 2
#define PLn 96
#define CINn 8
#define DFFn 2048
#define NTFn 4
#define EPSf 1e-5f

typedef __attribute__((ext_vector_type(8))) short short8v;
typedef __attribute__((ext_vector_type(4))) float f32x4;

__device__ __forceinline__ short f2b(float f) {
    union { float f; unsigned u; } v; v.f = f;
    unsigned r = v.u + 0x7fff + ((v.u >> 16) & 1);
    return (short)(r >> 16);
}
__device__ __forceinline__ float fast_tanh(float x) {
    float ax = fabsf(x);
    float e = __expf(2.f * ax);
    float t = 1.f - 2.f / (e + 1.f);
    return copysignf(t, x);
}

// ------------------------------------------------------- fp32 -> bf16
__global__ void cvt_kernel(const float* __restrict__ in, short* __restrict__ out, int n) {
    int i = blockIdx.x * 256 + threadIdx.x;
    if (i < n) out[i] = f2b(in[i]);
}

// ---------------------------------------------------------------- GARCH
__global__ void garch_kernel(const float* __restrict__ x_enc,
                             const float* __restrict__ g_omega,
                             const float* __restrict__ g_alpha,
                             const float* __restrict__ g_beta,
                             const float* __restrict__ g_h0,
                             float* __restrict__ garch) {
    int b = threadIdx.x;
    if (b >= Bn) return;
    float omega = log1pf(__expf(g_omega[0]));
    float alpha = 0.2f / (1.f + __expf(-g_alpha[0]));
    float beta  = 0.8f / (1.f + __expf(-g_beta[0]));
    float h = log1pf(__expf(g_h0[0]));
    const float* xe = x_enc + (size_t)b * Lq * CINn + (CINn - 2);
    for (int t = 0; t < Lq; ++t) {
        float r = xe[(size_t)t * CINn];
        h = omega + alpha * r * r + beta * h;
    }
    float ab = alpha + beta;
    for (int p = 0; p < PLn; ++p) {
        garch[b * PLn + p] = sqrtf(h);
        h = omega + ab * h;
    }
}

// ------------------------------------------------- conv + temporal + pos
__global__ void enc_kernel(const float* __restrict__ x_enc,
                           const float* __restrict__ x_mark,
                           const float* __restrict__ conv_w,
                           const float* __restrict__ temp_w,
                           float* __restrict__ enc) {
    int idx = blockIdx.x * blockDim.x + threadIdx.x;   // over B*L*D
    int d = idx & (Dm - 1);
    int l = (idx >> 7) & (Lq - 1);
    int b = idx >> 16;
    int lm = (l + Lq - 1) & (Lq - 1);
    int lp = (l + 1) & (Lq - 1);
    const float* xb = x_enc + (size_t)b * Lq * CINn;
    const float* w  = conv_w + (size_t)d * CINn * 3;
    float acc = 0.f;
#pragma unroll
    for (int ci = 0; ci < CINn; ++ci) {
        acc += xb[(size_t)lm * CINn + ci] * w[ci * 3 + 0];
        acc += xb[(size_t)l  * CINn + ci] * w[ci * 3 + 1];
        acc += xb[(size_t)lp * CINn + ci] * w[ci * 3 + 2];
    }
    const float* mk = x_mark + ((size_t)b * Lq + l) * NTFn;
    const float* tw = temp_w + (size_t)d * NTFn;
#pragma unroll
    for (int f = 0; f < NTFn; ++f) acc += mk[f] * tw[f];
    float dv = __expf(-(float)(d & ~1) * (9.210340371976184f / 128.f));
    float ang = (float)l * dv;
    acc += (d & 1) ? cosf(ang) : sinf(ang);
    enc[idx] = acc;
}

// ------------------------------------------ fp32 GEMM (kept for xW only)
#define BKt 64
#define LPAD 68
__global__ __launch_bounds__(256) void gemm_kernel(
    const float* __restrict__ A, const float* __restrict__ W,
    const float* __restrict__ b1, const float* __restrict__ b2,
    float* __restrict__ C, int M, int N, int K, int relu)
{
    __shared__ float As[BKt][LPAD];
    __shared__ float Ws[BKt][LPAD];
    int t  = threadIdx.x;
    int tr = t >> 4, tc = t & 15;
    int m0 = blockIdx.x * 64, n0 = blockIdx.y * 64;
    int lr  = t >> 4;
    int lc4 = (t & 15) * 4;
    float acc[4][4] = {};
    for (int k0 = 0; k0 < K; k0 += BKt) {
#pragma unroll
        for (int q = 0; q < 4; ++q) {
            int r = lr + q * 16;
            float4 av = *reinterpret_cast<const float4*>(&A[(size_t)(m0 + r) * K + k0 + lc4]);
            As[lc4 + 0][r] = av.x; As[lc4 + 1][r] = av.y;
            As[lc4 + 2][r] = av.z; As[lc4 + 3][r] = av.w;
            float4 wv = *reinterpret_cast<const float4*>(&W[(size_t)(n0 + r) * K + k0 + lc4]);
            Ws[lc4 + 0][r] = wv.x; Ws[lc4 + 1][r] = wv.y;
            Ws[lc4 + 2][r] = wv.z; Ws[lc4 + 3][r] = wv.w;
        }
        __syncthreads();
#pragma unroll 8
        for (int kk = 0; kk < BKt; ++kk) {
            float4 a  = *reinterpret_cast<const float4*>(&As[kk][tr * 4]);
            float4 bb = *reinterpret_cast<const float4*>(&Ws[kk][tc * 4]);
            float av[4] = {a.x, a.y, a.z, a.w};
            float bv[4] = {bb.x, bb.y, bb.z, bb.w};
#pragma unroll
            for (int i = 0; i < 4; ++i)
#pragma unroll
                for (int j = 0; j < 4; ++j)
                    acc[i][j] += av[i] * bv[j];
        }
        __syncthreads();
    }
#pragma unroll
    for (int i = 0; i < 4; ++i) {
        int m = m0 + tr * 4 + i;
#pragma unroll
        for (int j = 0; j < 4; ++j) {
            int n = n0 + tc * 4 + j;
            float v = acc[i][j] + b1[n] + (b2 ? b2[n] : 0.f);
            if (relu) v = fmaxf(v, 0.f);
            C[(size_t)m * N + n] = v;
        }
    }
}

// ------------------------ bf16 MFMA GEMM, tile 128x128 (4 waves of 64x64)
__global__ __launch_bounds__(256) void gemm_bf16_128(
    const short* __restrict__ A, const short* __restrict__ W,
    const float* __restrict__ b1,
    float* __restrict__ Cf, short* __restrict__ Cb,
    int M, int N, int K, int relu)
{
    int t = threadIdx.x;
    int wid = t >> 6, lane = t & 63;
    int wr = wid >> 1, wc = wid & 1;
    int m0 = blockIdx.x * 128 + wr * 64;
    int n0 = blockIdx.y * 128 + wc * 64;
    int lr = lane & 15;
    int lk = (lane >> 4) * 8;
    f32x4 acc[4][4] = {};
    for (int k0 = 0; k0 < K; k0 += 32) {
        short8v a[4], b[4];
#pragma unroll
        for (int i = 0; i < 4; ++i)
            a[i] = *reinterpret_cast<const short8v*>(&A[(size_t)(m0 + i * 16 + lr) * K + k0 + lk]);
#pragma unroll
        for (int j = 0; j < 4; ++j)
            b[j] = *reinterpret_cast<const short8v*>(&W[(size_t)(n0 + j * 16 + lr) * K + k0 + lk]);
#pragma unroll
        for (int i = 0; i < 4; ++i)
#pragma unroll
            for (int j = 0; j < 4; ++j)
                acc[i][j] = __builtin_amdgcn_mfma_f32_16x16x32_bf16(a[i], b[j], acc[i][j], 0, 0, 0);
    }
    int cr0 = (lane >> 4) * 4;
    int cc = lane & 15;
#pragma unroll
    for (int i = 0; i < 4; ++i)
#pragma unroll
        for (int j = 0; j < 4; ++j) {
            int col = n0 + j * 16 + cc;
            float bias = b1[col];
#pragma unroll
            for (int r = 0; r < 4; ++r) {
                int row = m0 + i * 16 + cr0 + r;
                float v = acc[i][j][r] + bias;
                if (relu) v = fmaxf(v, 0.f);
                if (Cf) Cf[(size_t)row * N + col] = v;
                else    Cb[(size_t)row * N + col] = f2b(v);
            }
        }
}

// ------------------------ bf16 MFMA GEMM, tile 64x64 (4 waves of 32x32)
__global__ __launch_bounds__(256) void gemm_bf16_64(
    const short* __restrict__ A, const short* __restrict__ W,
    const float* __restrict__ b1,
    float* __restrict__ Cf,
    int M, int N, int K)
{
    int t = threadIdx.x;
    int wid = t >> 6, lane = t & 63;
    int wr = wid >> 1, wc = wid & 1;
    int m0 = blockIdx.x * 64 + wr * 32;
    int n0 = blockIdx.y * 64 + wc * 32;
    int lr = lane & 15;
    int lk = (lane >> 4) * 8;
    f32x4 acc[2][2] = {};
    for (int k0 = 0; k0 < K; k0 += 32) {
        short8v a[2], b[2];
#pragma unroll
        for (int i = 0; i < 2; ++i)
            a[i] = *reinterpret_cast<const short8v*>(&A[(size_t)(m0 + i * 16 + lr) * K + k0 + lk]);
#pragma unroll
        for (int j = 0; j < 2; ++j)
            b[j] = *reinterpret_cast<const short8v*>(&W[(size_t)(n0 + j * 16 + lr) * K + k0 + lk]);
#pragma unroll
        for (int i = 0; i < 2; ++i)
#pragma unroll
            for (int j = 0; j < 2; ++j)
                acc[i][j] = __builtin_amdgcn_mfma_f32_16x16x32_bf16(a[i], b[j], acc[i][j], 0, 0, 0);
    }
    int cr0 = (lane >> 4) * 4;
    int cc = lane & 15;
#pragma unroll
    for (int i = 0; i < 2; ++i)
#pragma unroll
        for (int j = 0; j < 2; ++j) {
            int col = n0 + j * 16 + cc;
            float bias = b1[col];
#pragma unroll
            for (int r = 0; r < 4; ++r) {
                int row = m0 + i * 16 + cr0 + r;
                Cf[(size_t)row * N + col] = acc[i][j][r] + bias;
            }
        }
}

// ---------------------------------------------------------------- LSTM (MFMA matvec)
// 256 threads = 4 waves; wave w owns d in [w*32, w*32+32) for ALL 4 gates.
// Whh resident in A-fragments (VGPRs); h broadcast into B (all 16 cols equal);
// xW row prefetched from global directly into the MFMA accumulator (C-in).
__global__ __launch_bounds__(256, 1) void lstm_kernel(
    const float* __restrict__ xW, const short* __restrict__ Whh_b,
    float* __restrict__ xout, short* __restrict__ xb_out)
{
    __shared__ __align__(16) short hb[2][Dm];   // bf16 h, double-buffered
    __shared__ __align__(16) float gs[4][Dm];   // per-wave gate scratch [g*32 + d_off]
    int b = blockIdx.x;
    int tid = threadIdx.x;
    int w = tid >> 6;
    int lane = tid & 63;
    int lr = lane & 15;
    int lk = (lane >> 4) * 8;
    int cr0 = (lane >> 4) * 4;

    // A-fragments: tile (g,s): rows m0 = g*128 + w*32 + s*16, K=128 in 4 chunks of 32
    short8v a[4][2][4];
#pragma unroll
    for (int g = 0; g < 4; ++g)
#pragma unroll
        for (int s = 0; s < 2; ++s)
#pragma unroll
            for (int k = 0; k < 4; ++k)
                a[g][s][k] = *reinterpret_cast<const short8v*>(
                    &Whh_b[(size_t)(g * 128 + w * 32 + s * 16 + lr) * Dm + k * 32 + lk]);

    const float* xwb = xW + (size_t)b * Lq * 512;
    float cpers = 0.f;

    if (tid < 64) reinterpret_cast<int*>(hb[0])[tid] = 0;   // h(-1) = 0

    f32x4 xw0[4][2], xw1[4][2];
#pragma unroll
    for (int g = 0; g < 4; ++g)
#pragma unroll
        for (int s = 0; s < 2; ++s)
            xw0[g][s] = *reinterpret_cast<const f32x4*>(
                &xwb[(size_t)0 * 512 + g * 128 + w * 32 + s * 16 + cr0]);
    __syncthreads();

    auto step = [&](int t, f32x4 (&xwc)[4][2], f32x4 (&xwn)[4][2]) {
        int p = t & 1;
        // B-fragments: h bf16 broadcast (same for every lane / column)
        short8v bf[4];
#pragma unroll
        for (int k = 0; k < 4; ++k)
            bf[k] = *reinterpret_cast<const short8v*>(&hb[p][k * 32 + lk]);
        // prefetch next step's xW row into regs (off the critical path)
        int tn = (t + 1 < Lq) ? t + 1 : Lq - 1;
#pragma unroll
        for (int g = 0; g < 4; ++g)
#pragma unroll
            for (int s = 0; s < 2; ++s)
                xwn[g][s] = *reinterpret_cast<const f32x4*>(
                    &xwb[(size_t)tn * 512 + g * 128 + w * 32 + s * 16 + cr0]);
        // matvec: acc = Whh_tile . h + xw  (C-in = xw)
        f32x4 acc[4][2];
#pragma unroll
        for (int g = 0; g < 4; ++g)
#pragma unroll
            for (int s = 0; s < 2; ++s) {
                acc[g][s] = xwc[g][s];
#pragma unroll
                for (int k = 0; k < 4; ++k)
                    acc[g][s] = __builtin_amdgcn_mfma_f32_16x16x32_bf16(
                        a[g][s][k], bf[k], acc[g][s], 0, 0, 0);
            }
        // col-0 lanes export gate pre-activations to wave-private scratch
        if (lr == 0) {
#pragma unroll
            for (int g = 0; g < 4; ++g)
#pragma unroll
                for (int s = 0; s < 2; ++s)
                    *reinterpret_cast<f32x4*>(&gs[w][g * 32 + s * 16 + cr0]) = acc[g][s];
        }
        __syncthreads();
        // owner lanes: one hidden unit each
        if (lane < 32) {
            int d = w * 32 + lane;
            float iraw = gs[w][lane];
            float fraw = gs[w][32 + lane];
            float graw = gs[w][64 + lane];
            float oraw = gs[w][96 + lane];
            float ig = 1.f / (1.f + __expf(-iraw));
            float fg = 1.f / (1.f + __expf(-fraw));
            float gg = fast_tanh(graw);
            float og = 1.f / (1.f + __expf(-oraw));
            cpers = fg * cpers + ig * gg;
            float h = og * fast_tanh(cpers);
            size_t o = ((size_t)b * Lq + t) * Dm + d;
            float hnext = __shfl_down(h, 1);
            if (!(lane & 1)) {
                unsigned pk = (unsigned)(unsigned short)f2b(h) |
                              ((unsigned)(unsigned short)f2b(hnext) << 16);
                *reinterpret_cast<unsigned*>(&hb[p ^ 1][d]) = pk;
                *reinterpret_cast<unsigned*>(&xb_out[o]) = pk;
                float2 hv; hv.x = h; hv.y = hnext;
                *reinterpret_cast<float2*>(&xout[o]) = hv;
            }
        }
        __syncthreads();
    };

    for (int t = 0; t < Lq; t += 2) {
        step(t,     xw0, xw1);
        step(t + 1, xw1, xw0);
    }
}

// ------------------------------------------------------------- attention
__global__ __launch_bounds__(256) void attn_kernel(
    const float* __restrict__ qkv, short* __restrict__ ctxb)
{
    __shared__ float Kb[Lq][16];
    __shared__ float Vb[Lq][16];
    int h = blockIdx.x & (NHh - 1);
    int b = blockIdx.x >> 3;
    int t = threadIdx.x;
    const float* base = qkv + (size_t)b * Lq * 384;
    int hoff = h * 16;
    for (int idx = t; idx < Lq * 16; idx += 256) {
        int row = idx >> 4, col = idx & 15;
        Kb[row][col] = base[(size_t)row * 384 + 128 + hoff + col];
        Vb[row][col] = base[(size_t)row * 384 + 256 + hoff + col];
    }
    __syncthreads();
    for (int rr = 0; rr < 2; ++rr) {
        int l = t + rr * 256;
        float q[16];
#pragma unroll
        for (int cc = 0; cc < 16; ++cc) q[cc] = base[(size_t)l * 384 + hoff + cc];
        float m = -1e30f, ssum = 0.f;
        float acc[16] = {};
        for (int jr = 0; jr < Lq; ++jr) {
            float s = 0.f;
#pragma unroll
            for (int cc = 0; cc < 16; ++cc) s += q[cc] * Kb[jr][cc];
            s *= 0.25f;
            if (s > m) {
                float corr = __expf(m - s);
                ssum *= corr;
#pragma unroll
                for (int cc = 0; cc < 16; ++cc) acc[cc] *= corr;
                m = s;
            }
            float p = __expf(s - m);
            ssum += p;
#pragma unroll
            for (int cc = 0; cc < 16; ++cc) acc[cc] += p * Vb[jr][cc];
        }
        float inv = 1.f / ssum;
        short8v v0, v1;
#pragma unroll
        for (int cc = 0; cc < 8; ++cc) { v0[cc] = f2b(acc[cc] * inv); v1[cc] = f2b(acc[cc + 8] * inv); }
        short* o = ctxb + ((size_t)b * Lq + l) * Dm + hoff;
        *reinterpret_cast<short8v*>(o) = v0;
        *reinterpret_cast<short8v*>(o + 8) = v1;
    }
}

// ----------------------------------------------------- residual add + LN (+ bf16 mirror)
__global__ __launch_bounds__(256) void addln_kernel(
    float* __restrict__ x, const float* __restrict__ add,
    const float* __restrict__ g, const float* __restrict__ bta,
    short* __restrict__ xb)
{
    int wave = threadIdx.x >> 6;
    int lane = threadIdx.x & 63;
    int row = blockIdx.x * 4 + wave;
    float* xr = x + (size_t)row * Dm;
    const float* ar = add + (size_t)row * Dm;
    int d0 = lane * 2;
    float2 xv = *reinterpret_cast<const float2*>(&xr[d0]);
    float2 av = *reinterpret_cast<const float2*>(&ar[d0]);
    float v0 = xv.x + av.x, v1 = xv.y + av.y;
    float s = v0 + v1;
#pragma unroll
    for (int off = 32; off > 0; off >>= 1) s += __shfl_xor(s, off);
    float mu = s * (1.f / Dm);
    float e0 = v0 - mu, e1 = v1 - mu;
    float s2 = e0 * e0 + e1 * e1;
#pragma unroll
    for (int off = 32; off > 0; off >>= 1) s2 += __shfl_xor(s2, off);
    float rs = rsqrtf(s2 * (1.f / Dm) + EPSf);
    float o0 = e0 * rs * g[d0] + bta[d0];
    float o1 = e1 * rs * g[d0 + 1] + bta[d0 + 1];
    xr[d0] = o0;
    xr[d0 + 1] = o1;
    unsigned pk = (unsigned)(unsigned short)f2b(o0) | ((unsigned)(unsigned short)f2b(o1) << 16);
    *reinterpret_cast<unsigned*>(&xb[(size_t)row * Dm + d0]) = pk;
}

// --------------------------------------------------------------- head
__global__ void head_kernel(const float* __restrict__ x,
                            const float* __restrict__ head_w, const float* __restrict__ head_b,
                            const float* __restrict__ gw1, const float* __restrict__ gb1,
                            const float* __restrict__ gw2, const float* __restrict__ gb2,
                            const float* __restrict__ garch,
                            float* __restrict__ out)
{
    __shared__ float last[Dm];
    __shared__ float t1[Dm / 2];
    int b = blockIdx.x, t = threadIdx.x;
    if (t < Dm) last[t] = x[((size_t)b * Lq + (Lq - 1)) * Dm + t];
    __syncthreads();
    if (t < Dm / 2) {
        float s = gb1[t];
#pragma unroll 8
        for (int d = 0; d < Dm; ++d) s += last[d] * gw1[(size_t)t * Dm + d];
        t1[t] = fmaxf(s, 0.f);
    }
    __syncthreads();
    if (t < PLn) {
        float ai = head_b[t];
#pragma unroll 8
        for (int d = 0; d < Dm; ++d) ai += last[d] * head_w[(size_t)t * Dm + d];
        float gg = gb2[t];
#pragma unroll 8
        for (int j = 0; j < Dm / 2; ++j) gg += t1[j] * gw2[(size_t)t * (Dm / 2) + j];
        float gate = 1.f / (1.f + __expf(-gg));
        out[b * PLn + t] = garch[b * PLn + t] + gate * ai;
    }
}

extern "C" void kernel_launch(void* const* d_in, const int* in_sizes, int n_in,
                              void* d_out, int out_size, void* d_ws, size_t ws_size,
                              hipStream_t stream)
{
    const float* x_enc  = (const float*)d_in[0];
    const float* x_mark = (const float*)d_in[1];
    const float* conv_w = (const float*)d_in[4];
    const float* temp_w = (const float*)d_in[5];
    const float* Wih    = (const float*)d_in[6];
    const float* Whh    = (const float*)d_in[7];
    const float* bih    = (const float*)d_in[8];
    const float* bhh    = (const float*)d_in[9];
    const float* Wqkv   = (const float*)d_in[10];
    const float* bqkv   = (const float*)d_in[11];
    const float* Wo     = (const float*)d_in[12];
    const float* bo     = (const float*)d_in[13];
    const float* ln1g   = (const float*)d_in[14];
    const float* ln1b   = (const float*)d_in[15];
    const float* W1     = (const float*)d_in[16];
    const float* b1     = (const float*)d_in[17];
    const float* W2     = (const float*)d_in[18];
    const float* b2     = (const float*)d_in[19];
    const float* ln2g   = (const float*)d_in[20];
    const float* ln2b   = (const float*)d_in[21];
    const float* head_w = (const float*)d_in[22];
    const float* head_b = (const float*)d_in[23];
    const float* gw1    = (const float*)d_in[24];
    const float* gb1    = (const float*)d_in[25];
    const float* gw2    = (const float*)d_in[26];
    const float* gb2    = (const float*)d_in[27];
    const float* g_omega= (const float*)d_in[28];
    const float* g_alpha= (const float*)d_in[29];
    const float* g_beta = (const float*)d_in[30];
    const float* g_h0   = (const float*)d_in[31];

    const int M = Bn * Lq;                    // 32768
    float* ws    = (float*)d_ws;
    float* garch = ws;                        // 8192 floats
    float* regionA = ws + 8192;               // 4,194,304 floats
    float* enc  = regionA;                    //   fp32 enc (dead after xW gemm)
    short* xb   = (short*)regionA;            //   bf16 x mirror (after lstm)
    short* ctxb = (short*)(regionA + 2097152);//   bf16 ctx
    float* xWr  = regionA + 4194304;          // 16,777,216 floats
    float* xW   = xWr;                        //   fp32 xW (dead after lstm)
    short* ff1b = (short*)xWr;                //   bf16 ff1 chunk (16384x2048)
    float* x    = xWr + 16777216;             // 4,194,304 floats (live all launch)
    float* qkvr = x + 4194304;                // 12,582,912 floats
    float* qkv  = qkvr;                       //   fp32 qkv
    float* tmp  = qkvr;                       //   fp32 tmp (qkv dead when written)
    float* wbr  = qkvr + 12582912;            // bf16 weight mirrors
    short* Wqkv_b = (short*)wbr;              // 98,304
    short* Wo_b   = Wqkv_b + 98304;           // 32,768
    short* W1_b   = Wo_b + 32768;             // 524,288
    short* W2_b   = W1_b + 524288;            // 524,288
    short* Whh_bb = W2_b + 524288;            // 65,536

    cvt_kernel<<<(98304 + 255) / 256, 256, 0, stream>>>(Wqkv, Wqkv_b, 98304);
    cvt_kernel<<<(32768 + 255) / 256, 256, 0, stream>>>(Wo, Wo_b, 32768);
    cvt_kernel<<<(524288 + 255) / 256, 256, 0, stream>>>(W1, W1_b, 524288);
    cvt_kernel<<<(524288 + 255) / 256, 256, 0, stream>>>(W2, W2_b, 524288);
    cvt_kernel<<<(65536 + 255) / 256, 256, 0, stream>>>(Whh, Whh_bb, 65536);

    garch_kernel<<<1, 64, 0, stream>>>(x_enc, g_omega, g_alpha, g_beta, g_h0, garch);
    enc_kernel<<<(Bn * Lq * Dm) / 256, 256, 0, stream>>>(x_enc, x_mark, conv_w, temp_w, enc);
    gemm_kernel<<<dim3(M / 64, 512 / 64), 256, 0, stream>>>(enc, Wih, bih, bhh, xW, M, 512, Dm, 0);
    lstm_kernel<<<Bn, 256, 0, stream>>>(xW, Whh_bb, x, xb);

    for (int li = 0; li < ELn; ++li) {
        gemm_bf16_128<<<dim3(M / 128, 384 / 128), 256, 0, stream>>>(
            xb, Wqkv_b + (size_t)li * 384 * Dm, bqkv + li * 384, qkv, nullptr, M, 384, Dm, 0);
        attn_kernel<<<Bn * NHh, 256, 0, stream>>>(qkv, ctxb);
        gemm_bf16_64<<<dim3(M / 64, Dm / 64), 256, 0, stream>>>(
            ctxb, Wo_b + (size_t)li * Dm * Dm, bo + li * Dm, tmp, M, Dm, Dm);
        addln_kernel<<<M / 4, 256, 0, stream>>>(x, tmp, ln1g + li * Dm, ln1b + li * Dm, xb);
        for (int mc = 0; mc < 2; ++mc) {
            const int MC = M / 2;             // 16384 rows
            gemm_bf16_128<<<dim3(MC / 128, DFFn / 128), 256, 0, stream>>>(
                xb + (size_t)mc * MC * Dm, W1_b + (size_t)li * DFFn * Dm, b1 + li * DFFn,
                nullptr, ff1b, MC, DFFn, Dm, 1);
            gemm_bf16_64<<<dim3(MC / 64, Dm / 64), 256, 0, stream>>>(
                ff1b, W2_b + (size_t)li * Dm * DFFn, b2 + li * Dm,
                tmp + (size_t)mc * MC * Dm, MC, Dm, DFFn);
        }
        addln_kernel<<<M / 4, 256, 0, stream>>>(x, tmp, ln2g + li * Dm, ln2b + li * Dm, xb);
    }
    head_kernel<<<Bn, 128, 0, stream>>>(x, head_w, head_b, gw1, gb1, gw2, gb2, garch,
                                        (float*)d_out);
}

// Round 9
// 1500.884 us; speedup vs baseline: 1.1842x; 1.0450x over previous
//
#include <hip/hip_runtime.h>
#include <hip/hip_bf16.h>
#include <math.h>

#define Bn 64
#define Lq 512
#define Dm 128
#define NHh 8
#define ELn 2
#define PLn 96
#define CINn 8
#define DFFn 2048
#define NTFn 4
#define EPSf 1e-5f

typedef __attribute__((ext_vector_type(8))) short short8v;
typedef __attribute__((ext_vector_type(4))) float f32x4;

__device__ __forceinline__ short f2b(float f) {
    union { float f; unsigned u; } v; v.f = f;
    unsigned r = v.u + 0x7fff + ((v.u >> 16) & 1);
    return (short)(r >> 16);
}
__device__ __forceinline__ float fast_tanh(float x) {
    float ax = fabsf(x);
    float e = __expf(2.f * ax);
    float t = 1.f - 2.f / (e + 1.f);
    return copysignf(t, x);
}

// ------------------------------------------------------- fp32 -> bf16
__global__ void cvt_kernel(const float* __restrict__ in, short* __restrict__ out, int n) {
    int i = blockIdx.x * 256 + threadIdx.x;
    if (i < n) out[i] = f2b(in[i]);
}

// ------------------------------------------------------- bias sum (bih+bhh)
__global__ void biassum_kernel(const float* __restrict__ a, const float* __restrict__ b,
                               float* __restrict__ o, int n) {
    int i = blockIdx.x * 256 + threadIdx.x;
    if (i < n) o[i] = a[i] + b[i];
}

// ---------------------------------------------------------------- GARCH
__global__ void garch_kernel(const float* __restrict__ x_enc,
                             const float* __restrict__ g_omega,
                             const float* __restrict__ g_alpha,
                             const float* __restrict__ g_beta,
                             const float* __restrict__ g_h0,
                             float* __restrict__ garch) {
    int b = threadIdx.x;
    if (b >= Bn) return;
    float omega = log1pf(__expf(g_omega[0]));
    float alpha = 0.2f / (1.f + __expf(-g_alpha[0]));
    float beta  = 0.8f / (1.f + __expf(-g_beta[0]));
    float h = log1pf(__expf(g_h0[0]));
    const float* xe = x_enc + (size_t)b * Lq * CINn + (CINn - 2);
    for (int t = 0; t < Lq; ++t) {
        float r = xe[(size_t)t * CINn];
        h = omega + alpha * r * r + beta * h;
    }
    float ab = alpha + beta;
    for (int p = 0; p < PLn; ++p) {
        garch[b * PLn + p] = sqrtf(h);
        h = omega + ab * h;
    }
}

// ------------------------------------------------- conv + temporal + pos (bf16 out)
__global__ void enc_kernel(const float* __restrict__ x_enc,
                           const float* __restrict__ x_mark,
                           const float* __restrict__ conv_w,
                           const float* __restrict__ temp_w,
                           short* __restrict__ encb) {
    int idx = blockIdx.x * blockDim.x + threadIdx.x;   // over B*L*D
    int d = idx & (Dm - 1);
    int l = (idx >> 7) & (Lq - 1);
    int b = idx >> 16;
    int lm = (l + Lq - 1) & (Lq - 1);
    int lp = (l + 1) & (Lq - 1);
    const float* xb = x_enc + (size_t)b * Lq * CINn;
    const float* w  = conv_w + (size_t)d * CINn * 3;
    float acc = 0.f;
#pragma unroll
    for (int ci = 0; ci < CINn; ++ci) {
        acc += xb[(size_t)lm * CINn + ci] * w[ci * 3 + 0];
        acc += xb[(size_t)l  * CINn + ci] * w[ci * 3 + 1];
        acc += xb[(size_t)lp * CINn + ci] * w[ci * 3 + 2];
    }
    const float* mk = x_mark + ((size_t)b * Lq + l) * NTFn;
    const float* tw = temp_w + (size_t)d * NTFn;
#pragma unroll
    for (int f = 0; f < NTFn; ++f) acc += mk[f] * tw[f];
    float dv = __expf(-(float)(d & ~1) * (9.210340371976184f / 128.f));
    float ang = (float)l * dv;
    acc += (d & 1) ? cosf(ang) : sinf(ang);
    encb[idx] = f2b(acc);
}

// ------------------------ bf16 MFMA GEMM, tile 128x128 (4 waves of 64x64)
__global__ __launch_bounds__(256) void gemm_bf16_128(
    const short* __restrict__ A, const short* __restrict__ W,
    const float* __restrict__ b1,
    float* __restrict__ Cf, short* __restrict__ Cb,
    int M, int N, int K, int relu)
{
    int t = threadIdx.x;
    int wid = t >> 6, lane = t & 63;
    int wr = wid >> 1, wc = wid & 1;
    int m0 = blockIdx.x * 128 + wr * 64;
    int n0 = blockIdx.y * 128 + wc * 64;
    int lr = lane & 15;
    int lk = (lane >> 4) * 8;
    f32x4 acc[4][4] = {};
    for (int k0 = 0; k0 < K; k0 += 32) {
        short8v a[4], b[4];
#pragma unroll
        for (int i = 0; i < 4; ++i)
            a[i] = *reinterpret_cast<const short8v*>(&A[(size_t)(m0 + i * 16 + lr) * K + k0 + lk]);
#pragma unroll
        for (int j = 0; j < 4; ++j)
            b[j] = *reinterpret_cast<const short8v*>(&W[(size_t)(n0 + j * 16 + lr) * K + k0 + lk]);
#pragma unroll
        for (int i = 0; i < 4; ++i)
#pragma unroll
            for (int j = 0; j < 4; ++j)
                acc[i][j] = __builtin_amdgcn_mfma_f32_16x16x32_bf16(a[i], b[j], acc[i][j], 0, 0, 0);
    }
    int cr0 = (lane >> 4) * 4;
    int cc = lane & 15;
#pragma unroll
    for (int i = 0; i < 4; ++i)
#pragma unroll
        for (int j = 0; j < 4; ++j) {
            int col = n0 + j * 16 + cc;
            float bias = b1[col];
#pragma unroll
            for (int r = 0; r < 4; ++r) {
                int row = m0 + i * 16 + cr0 + r;
                float v = acc[i][j][r] + bias;
                if (relu) v = fmaxf(v, 0.f);
                if (Cf) Cf[(size_t)row * N + col] = v;
                else    Cb[(size_t)row * N + col] = f2b(v);
            }
        }
}

// ------------------------ bf16 MFMA GEMM, tile 64x64 (4 waves of 32x32)
__global__ __launch_bounds__(256) void gemm_bf16_64(
    const short* __restrict__ A, const short* __restrict__ W,
    const float* __restrict__ b1,
    float* __restrict__ Cf,
    int M, int N, int K)
{
    int t = threadIdx.x;
    int wid = t >> 6, lane = t & 63;
    int wr = wid >> 1, wc = wid & 1;
    int m0 = blockIdx.x * 64 + wr * 32;
    int n0 = blockIdx.y * 64 + wc * 32;
    int lr = lane & 15;
    int lk = (lane >> 4) * 8;
    f32x4 acc[2][2] = {};
    for (int k0 = 0; k0 < K; k0 += 32) {
        short8v a[2], b[2];
#pragma unroll
        for (int i = 0; i < 2; ++i)
            a[i] = *reinterpret_cast<const short8v*>(&A[(size_t)(m0 + i * 16 + lr) * K + k0 + lk]);
#pragma unroll
        for (int j = 0; j < 2; ++j)
            b[j] = *reinterpret_cast<const short8v*>(&W[(size_t)(n0 + j * 16 + lr) * K + k0 + lk]);
#pragma unroll
        for (int i = 0; i < 2; ++i)
#pragma unroll
            for (int j = 0; j < 2; ++j)
                acc[i][j] = __builtin_amdgcn_mfma_f32_16x16x32_bf16(a[i], b[j], acc[i][j], 0, 0, 0);
    }
    int cr0 = (lane >> 4) * 4;
    int cc = lane & 15;
#pragma unroll
    for (int i = 0; i < 2; ++i)
#pragma unroll
        for (int j = 0; j < 2; ++j) {
            int col = n0 + j * 16 + cc;
            float bias = b1[col];
#pragma unroll
            for (int r = 0; r < 4; ++r) {
                int row = m0 + i * 16 + cr0 + r;
                Cf[(size_t)row * N + col] = acc[i][j][r] + bias;
            }
        }
}

// ---------------------------------------------------------------- LSTM (MFMA matvec v2)
// 256 threads = 4 waves; wave w owns d in [w*32, w*32+32) for ALL 4 gates.
// MFMA output columns are 16 redundant copies (B cols identical) -> copy q=lane&15
// (q<8) owns (s,r)=(q>>2,q&3): activations fully in-register, ONE barrier/step,
// raw s_barrier without vmcnt drain so the distance-2 xW prefetch stays in flight.
__global__ __launch_bounds__(256, 1) void lstm_kernel(
    const float* __restrict__ xW, const short* __restrict__ Whh_b,
    float* __restrict__ xout, short* __restrict__ xb_out)
{
    __shared__ __align__(16) short hb[2][Dm];   // bf16 h, double-buffered
    int b = blockIdx.x;
    int tid = threadIdx.x;
    int w = tid >> 6;
    int lane = tid & 63;
    int lr = lane & 15;
    int lk = (lane >> 4) * 8;
    int cr0 = (lane >> 4) * 4;
    int qs = lr >> 2;         // owned s (valid when lr<8)
    int qr = lr & 3;          // owned r

    // A-fragments: tile (g,s): rows m0 = g*128 + w*32 + s*16, K=128 in 4 chunks of 32
    short8v a[4][2][4];
#pragma unroll
    for (int g = 0; g < 4; ++g)
#pragma unroll
        for (int s = 0; s < 2; ++s)
#pragma unroll
            for (int k = 0; k < 4; ++k)
                a[g][s][k] = *reinterpret_cast<const short8v*>(
                    &Whh_b[(size_t)(g * 128 + w * 32 + s * 16 + lr) * Dm + k * 32 + lk]);

    const float* xwb = xW + (size_t)b * Lq * 512;
    float cpers = 0.f;
    if (tid < 64) reinterpret_cast<int*>(hb[0])[tid] = 0;   // h(-1) = 0

    f32x4 xwA[4][2], xwB[4][2];
#pragma unroll
    for (int g = 0; g < 4; ++g)
#pragma unroll
        for (int s = 0; s < 2; ++s) {
            xwA[g][s] = *reinterpret_cast<const f32x4*>(
                &xwb[(size_t)0 * 512 + g * 128 + w * 32 + s * 16 + cr0]);
            xwB[g][s] = *reinterpret_cast<const f32x4*>(
                &xwb[(size_t)1 * 512 + g * 128 + w * 32 + s * 16 + cr0]);
        }
    __syncthreads();

    auto step = [&](int t, f32x4 (&xwC)[4][2]) {
        int p = t & 1;
        // B-fragments: h bf16 broadcast (identical across lanes/cols)
        short8v bf[4];
#pragma unroll
        for (int k = 0; k < 4; ++k)
            bf[k] = *reinterpret_cast<const short8v*>(&hb[p][k * 32 + lk]);
        // move C-in to acc, then reuse xwC's registers for the t+2 prefetch
        f32x4 acc[4][2];
#pragma unroll
        for (int g = 0; g < 4; ++g)
#pragma unroll
            for (int s = 0; s < 2; ++s)
                acc[g][s] = xwC[g][s];
        int tp = (t + 2 < Lq) ? t + 2 : Lq - 1;
#pragma unroll
        for (int g = 0; g < 4; ++g)
#pragma unroll
            for (int s = 0; s < 2; ++s)
                xwC[g][s] = *reinterpret_cast<const f32x4*>(
                    &xwb[(size_t)tp * 512 + g * 128 + w * 32 + s * 16 + cr0]);
        // matvec: acc += Whh_tile . h
#pragma unroll
        for (int g = 0; g < 4; ++g)
#pragma unroll
            for (int s = 0; s < 2; ++s)
#pragma unroll
                for (int k = 0; k < 4; ++k)
                    acc[g][s] = __builtin_amdgcn_mfma_f32_16x16x32_bf16(
                        a[g][s][k], bf[k], acc[g][s], 0, 0, 0);
        // owned-copy lanes: activations in-register (static-index selects)
        if (lr < 8) {
            float iraw = 0.f, fraw = 0.f, graw = 0.f, oraw = 0.f;
#pragma unroll
            for (int s = 0; s < 2; ++s)
#pragma unroll
                for (int r = 0; r < 4; ++r)
                    if (qs == s && qr == r) {
                        iraw = acc[0][s][r]; fraw = acc[1][s][r];
                        graw = acc[2][s][r]; oraw = acc[3][s][r];
                    }
            float ig = 1.f / (1.f + __expf(-iraw));
            float fg = 1.f / (1.f + __expf(-fraw));
            float gg = fast_tanh(graw);
            float og = 1.f / (1.f + __expf(-oraw));
            cpers = fg * cpers + ig * gg;
            float h = og * fast_tanh(cpers);
            int d = w * 32 + qs * 16 + cr0 + qr;
            short hv = f2b(h);
            hb[p ^ 1][d] = hv;
            size_t o = ((size_t)b * Lq + t) * Dm + d;
            xb_out[o] = hv;
            xout[o] = h;
        }
        // LDS visibility only; vmcnt stays un-drained (prefetch in flight)
        asm volatile("s_waitcnt lgkmcnt(0)" ::: "memory");
        __builtin_amdgcn_s_barrier();
    };

    for (int t = 0; t < Lq; t += 2) {
        step(t, xwA);
        step(t + 1, xwB);
    }
}

// ------------------------------------------------------------- attention
__global__ __launch_bounds__(256) void attn_kernel(
    const float* __restrict__ qkv, short* __restrict__ ctxb)
{
    __shared__ float Kb[Lq][16];
    __shared__ float Vb[Lq][16];
    int h = blockIdx.x & (NHh - 1);
    int b = blockIdx.x >> 3;
    int t = threadIdx.x;
    const float* base = qkv + (size_t)b * Lq * 384;
    int hoff = h * 16;
    for (int idx = t; idx < Lq * 16; idx += 256) {
        int row = idx >> 4, col = idx & 15;
        Kb[row][col] = base[(size_t)row * 384 + 128 + hoff + col];
        Vb[row][col] = base[(size_t)row * 384 + 256 + hoff + col];
    }
    __syncthreads();
    for (int rr = 0; rr < 2; ++rr) {
        int l = t + rr * 256;
        float q[16];
#pragma unroll
        for (int cc = 0; cc < 16; ++cc) q[cc] = base[(size_t)l * 384 + hoff + cc];
        float m = -1e30f, ssum = 0.f;
        float acc[16] = {};
        for (int jr = 0; jr < Lq; ++jr) {
            float s = 0.f;
#pragma unroll
            for (int cc = 0; cc < 16; ++cc) s += q[cc] * Kb[jr][cc];
            s *= 0.25f;
            if (s > m) {
                float corr = __expf(m - s);
                ssum *= corr;
#pragma unroll
                for (int cc = 0; cc < 16; ++cc) acc[cc] *= corr;
                m = s;
            }
            float p = __expf(s - m);
            ssum += p;
#pragma unroll
            for (int cc = 0; cc < 16; ++cc) acc[cc] += p * Vb[jr][cc];
        }
        float inv = 1.f / ssum;
        short8v v0, v1;
#pragma unroll
        for (int cc = 0; cc < 8; ++cc) { v0[cc] = f2b(acc[cc] * inv); v1[cc] = f2b(acc[cc + 8] * inv); }
        short* o = ctxb + ((size_t)b * Lq + l) * Dm + hoff;
        *reinterpret_cast<short8v*>(o) = v0;
        *reinterpret_cast<short8v*>(o + 8) = v1;
    }
}

// ----------------------------------------------------- residual add + LN (+ bf16 mirror)
__global__ __launch_bounds__(256) void addln_kernel(
    float* __restrict__ x, const float* __restrict__ add,
    const float* __restrict__ g, const float* __restrict__ bta,
    short* __restrict__ xb)
{
    int wave = threadIdx.x >> 6;
    int lane = threadIdx.x & 63;
    int row = blockIdx.x * 4 + wave;
    float* xr = x + (size_t)row * Dm;
    const float* ar = add + (size_t)row * Dm;
    int d0 = lane * 2;
    float2 xv = *reinterpret_cast<const float2*>(&xr[d0]);
    float2 av = *reinterpret_cast<const float2*>(&ar[d0]);
    float v0 = xv.x + av.x, v1 = xv.y + av.y;
    float s = v0 + v1;
#pragma unroll
    for (int off = 32; off > 0; off >>= 1) s += __shfl_xor(s, off);
    float mu = s * (1.f / Dm);
    float e0 = v0 - mu, e1 = v1 - mu;
    float s2 = e0 * e0 + e1 * e1;
#pragma unroll
    for (int off = 32; off > 0; off >>= 1) s2 += __shfl_xor(s2, off);
    float rs = rsqrtf(s2 * (1.f / Dm) + EPSf);
    float o0 = e0 * rs * g[d0] + bta[d0];
    float o1 = e1 * rs * g[d0 + 1] + bta[d0 + 1];
    xr[d0] = o0;
    xr[d0 + 1] = o1;
    unsigned pk = (unsigned)(unsigned short)f2b(o0) | ((unsigned)(unsigned short)f2b(o1) << 16);
    *reinterpret_cast<unsigned*>(&xb[(size_t)row * Dm + d0]) = pk;
}

// --------------------------------------------------------------- head
__global__ void head_kernel(const float* __restrict__ x,
                            const float* __restrict__ head_w, const float* __restrict__ head_b,
                            const float* __restrict__ gw1, const float* __restrict__ gb1,
                            const float* __restrict__ gw2, const float* __restrict__ gb2,
                            const float* __restrict__ garch,
                            float* __restrict__ out)
{
    __shared__ float last[Dm];
    __shared__ float t1[Dm / 2];
    int b = blockIdx.x, t = threadIdx.x;
    if (t < Dm) last[t] = x[((size_t)b * Lq + (Lq - 1)) * Dm + t];
    __syncthreads();
    if (t < Dm / 2) {
        float s = gb1[t];
#pragma unroll 8
        for (int d = 0; d < Dm; ++d) s += last[d] * gw1[(size_t)t * Dm + d];
        t1[t] = fmaxf(s, 0.f);
    }
    __syncthreads();
    if (t < PLn) {
        float ai = head_b[t];
#pragma unroll 8
        for (int d = 0; d < Dm; ++d) ai += last[d] * head_w[(size_t)t * Dm + d];
        float gg = gb2[t];
#pragma unroll 8
        for (int j = 0; j < Dm / 2; ++j) gg += t1[j] * gw2[(size_t)t * (Dm / 2) + j];
        float gate = 1.f / (1.f + __expf(-gg));
        out[b * PLn + t] = garch[b * PLn + t] + gate * ai;
    }
}

extern "C" void kernel_launch(void* const* d_in, const int* in_sizes, int n_in,
                              void* d_out, int out_size, void* d_ws, size_t ws_size,
                              hipStream_t stream)
{
    const float* x_enc  = (const float*)d_in[0];
    const float* x_mark = (const float*)d_in[1];
    const float* conv_w = (const float*)d_in[4];
    const float* temp_w = (const float*)d_in[5];
    const float* Wih    = (const float*)d_in[6];
    const float* Whh    = (const float*)d_in[7];
    const float* bih    = (const float*)d_in[8];
    const float* bhh    = (const float*)d_in[9];
    const float* Wqkv   = (const float*)d_in[10];
    const float* bqkv   = (const float*)d_in[11];
    const float* Wo     = (const float*)d_in[12];
    const float* bo     = (const float*)d_in[13];
    const float* ln1g   = (const float*)d_in[14];
    const float* ln1b   = (const float*)d_in[15];
    const float* W1     = (const float*)d_in[16];
    const float* b1     = (const float*)d_in[17];
    const float* W2     = (const float*)d_in[18];
    const float* b2     = (const float*)d_in[19];
    const float* ln2g   = (const float*)d_in[20];
    const float* ln2b   = (const float*)d_in[21];
    const float* head_w = (const float*)d_in[22];
    const float* head_b = (const float*)d_in[23];
    const float* gw1    = (const float*)d_in[24];
    const float* gb1    = (const float*)d_in[25];
    const float* gw2    = (const float*)d_in[26];
    const float* gb2    = (const float*)d_in[27];
    const float* g_omega= (const float*)d_in[28];
    const float* g_alpha= (const float*)d_in[29];
    const float* g_beta = (const float*)d_in[30];
    const float* g_h0   = (const float*)d_in[31];

    const int M = Bn * Lq;                    // 32768
    float* ws    = (float*)d_ws;
    float* garch = ws;                        // 6144 used
    float* biassum = ws + 6144;               // 512 floats (bih+bhh)
    float* regionA = ws + 8192;               // 4,194,304 floats
    short* xb   = (short*)regionA;            //   bf16 x mirror (after lstm)
    short* ctxb = (short*)(regionA + 2097152);//   bf16 ctx
    float* xWr  = regionA + 4194304;          // 16,777,216 floats
    float* xW   = xWr;                        //   fp32 xW (dead after lstm)
    short* ff1b = (short*)xWr;                //   bf16 ff1 chunk (16384x2048)
    float* x    = xWr + 16777216;             // 4,194,304 floats (live all launch)
    float* qkvr = x + 4194304;                // 12,582,912 floats
    short* encb = (short*)qkvr;               //   bf16 enc (dead after xW gemm)
    float* qkv  = qkvr;                       //   fp32 qkv
    float* tmp  = qkvr;                       //   fp32 tmp (qkv dead when written)
    float* wbr  = qkvr + 12582912;            // bf16 weight mirrors
    short* Wqkv_b = (short*)wbr;              // 98,304
    short* Wo_b   = Wqkv_b + 98304;           // 32,768
    short* W1_b   = Wo_b + 32768;             // 524,288
    short* W2_b   = W1_b + 524288;            // 524,288
    short* Whh_bb = W2_b + 524288;            // 65,536
    short* Wih_b  = Whh_bb + 65536;           // 65,536

    cvt_kernel<<<(98304 + 255) / 256, 256, 0, stream>>>(Wqkv, Wqkv_b, 98304);
    cvt_kernel<<<(32768 + 255) / 256, 256, 0, stream>>>(Wo, Wo_b, 32768);
    cvt_kernel<<<(524288 + 255) / 256, 256, 0, stream>>>(W1, W1_b, 524288);
    cvt_kernel<<<(524288 + 255) / 256, 256, 0, stream>>>(W2, W2_b, 524288);
    cvt_kernel<<<(65536 + 255) / 256, 256, 0, stream>>>(Whh, Whh_bb, 65536);
    cvt_kernel<<<(65536 + 255) / 256, 256, 0, stream>>>(Wih, Wih_b, 65536);
    biassum_kernel<<<2, 256, 0, stream>>>(bih, bhh, biassum, 512);

    garch_kernel<<<1, 64, 0, stream>>>(x_enc, g_omega, g_alpha, g_beta, g_h0, garch);
    enc_kernel<<<(Bn * Lq * Dm) / 256, 256, 0, stream>>>(x_enc, x_mark, conv_w, temp_w, encb);
    gemm_bf16_128<<<dim3(M / 128, 512 / 128), 256, 0, stream>>>(
        encb, Wih_b, biassum, xW, nullptr, M, 512, Dm, 0);
    lstm_kernel<<<Bn, 256, 0, stream>>>(xW, Whh_bb, x, xb);

    for (int li = 0; li < ELn; ++li) {
        gemm_bf16_128<<<dim3(M / 128, 384 / 128), 256, 0, stream>>>(
            xb, Wqkv_b + (size_t)li * 384 * Dm, bqkv + li * 384, qkv, nullptr, M, 384, Dm, 0);
        attn_kernel<<<Bn * NHh, 256, 0, stream>>>(qkv, ctxb);
        gemm_bf16_64<<<dim3(M / 64, Dm / 64), 256, 0, stream>>>(
            ctxb, Wo_b + (size_t)li * Dm * Dm, bo + li * Dm, tmp, M, Dm, Dm);
        addln_kernel<<<M / 4, 256, 0, stream>>>(x, tmp, ln1g + li * Dm, ln1b + li * Dm, xb);
        for (int mc = 0; mc < 2; ++mc) {
            const int MC = M / 2;             // 16384 rows
            gemm_bf16_128<<<dim3(MC / 128, DFFn / 128), 256, 0, stream>>>(
                xb + (size_t)mc * MC * Dm, W1_b + (size_t)li * DFFn * Dm, b1 + li * DFFn,
                nullptr, ff1b, MC, DFFn, Dm, 1);
            gemm_bf16_64<<<dim3(MC / 64, Dm / 64), 256, 0, stream>>>(
                ff1b, W2_b + (size_t)li * Dm * DFFn, b2 + li * Dm,
                tmp + (size_t)mc * MC * Dm, MC, Dm, DFFn);
        }
        addln_kernel<<<M / 4, 256, 0, stream>>>(x, tmp, ln2g + li * Dm, ln2b + li * Dm, xb);
    }
    head_kernel<<<Bn, 128, 0, stream>>>(x, head_w, head_b, gw1, gb1, gw2, gb2, garch,
                                        (float*)d_out);
}